// Round 1
// baseline (717.703 us; speedup 1.0000x reference)
//
#include <hip/hip_runtime.h>

// NuclideGNN: 3-layer GCN on MI355X.
// R9: (a) hB rows pre-scaled by dinv[src] in GEMM epilogue -> gather is pure
//     row-sum; (b) p1+p3 fused into one LDS-staged pass with fixed 20k-edge
//     bucket windows.
// R10: XCD-affine column-split gather. Block 2n+h aggregates cols
//     [h*W, h*W+W) of node n (W = DO/2). Even/odd blocks land on even/odd
//     XCDs (round-robin heuristic), halving the per-XCD gather working set:
//     12.8->6.4 MB (DO=128), 6.4->3.2 MB (DO=64, fully L2-resident).
//     Predicted: FETCH 200->~150 MB on DO=128 gathers, dur 83.7->~68 us.

#define NN 100000
#define NE 3200000
#define FI 7
#define HD 128
#define DD 64
#define EPS 1e-5f
#define NB 196                        // buckets of 512 dst nodes (dst>>9)
#define EPB 8192                      // edges per pA block (256 thr x 32)
#define NBLK ((NE + EPB - 1) / EPB)   // 391
#define EMAX 20000                    // fixed ebin window per bucket (max ~16.7k)

typedef float float2v __attribute__((ext_vector_type(2)));
typedef short short8 __attribute__((ext_vector_type(8)));
typedef float f32x4 __attribute__((ext_vector_type(4)));

__device__ __forceinline__ unsigned char f2fp8(float f) {
    return (unsigned char)(__builtin_amdgcn_cvt_pk_fp8_f32(f, f, 0, false) & 0xFF);
}
__device__ __forceinline__ unsigned short f2bf(float f) {
    unsigned u = __float_as_uint(f);
    u += 0x7FFF + ((u >> 16) & 1);  // RNE
    return (unsigned short)(u >> 16);
}

// ---------------- CSR build ----------------
// pA: single pass: stage dst in LDS, hist, reserve fixed bucket windows,
//     scatter packed (local-dst | src) records.

__global__ __launch_bounds__(256) void pA_bin(const int* __restrict__ ei,
                                              int* __restrict__ bcnt,
                                              int* __restrict__ ebin) {
    __shared__ int sdst[EPB];   // 32 KB
    __shared__ int hcur[NB];
    const int t = threadIdx.x;
    for (int b = t; b < NB; b += 256) hcur[b] = 0;
    __syncthreads();
    const int base = blockIdx.x * EPB;
    const int cnt = min(EPB, NE - base);
    for (int i = t; i < cnt; i += 256) {
        int d = ei[NE + base + i];
        sdst[i] = d;
        atomicAdd(&hcur[d >> 9], 1);
    }
    __syncthreads();
    for (int b = t; b < NB; b += 256) {
        int c = hcur[b];
        hcur[b] = (c ? atomicAdd(&bcnt[b], c) : 0) + b * EMAX;
    }
    __syncthreads();
    for (int i = t; i < cnt; i += 256) {
        int s = ei[base + i];
        int d = sdst[i];
        int p = atomicAdd(&hcur[d >> 9], 1);
        ebin[p] = ((d & 511) << 23) | s;
    }
}

// p4: local bucket scan (dense esrc offsets) + per-bucket hist/scan/scatter.
__global__ __launch_bounds__(512) void p4_finalize(const int* __restrict__ bcnt,
                                                   const int* __restrict__ ebin,
                                                   int* __restrict__ esrc,
                                                   int* __restrict__ rowstart,
                                                   float* __restrict__ dinv) {
    __shared__ int sh[256];  // bucket-count scan
    __shared__ int lh[512];  // local degree
    __shared__ int sc[512];  // scan buffer
    __shared__ int lc[512];  // local cursor
    const int t = threadIdx.x;
    const int b = blockIdx.x;
    if (t < 256) sh[t] = (t < NB) ? bcnt[t] : 0;
    __syncthreads();
    for (int off = 1; off < 256; off <<= 1) {
        int v = (t < 256 && t >= off) ? sh[t - off] : 0;
        __syncthreads();
        if (t < 256) sh[t] += v;
        __syncthreads();
    }
    const int ecnt = bcnt[b];
    const int ebase = sh[b] - ecnt;   // dense esrc base for this bucket
    const int rbase = b * EMAX;       // padded ebin read base
    const int n0 = b << 9;
    lh[t] = 0;
    __syncthreads();
    for (int i = t; i < ecnt; i += 512)
        atomicAdd(&lh[((unsigned)ebin[rbase + i]) >> 23], 1);
    __syncthreads();
    const int c = lh[t];
    sc[t] = c;
    __syncthreads();
    for (int off = 1; off < 512; off <<= 1) {
        int v = (t >= off) ? sc[t - off] : 0;
        __syncthreads();
        sc[t] += v;
        __syncthreads();
    }
    const int excl = ebase + sc[t] - c;  // global rowstart for node n0+t
    lc[t] = excl;
    const int node = n0 + t;
    if (node < NN) {
        rowstart[node] = excl;
        dinv[node] = rsqrtf((float)c + 1.0f);  // deg includes self-loop
    }
    if (b == NB - 1 && t == 0) rowstart[NN] = NE;
    __syncthreads();
    for (int i = t; i < ecnt; i += 512) {
        int v = ebin[rbase + i];
        int p = atomicAdd(&lc[((unsigned)v) >> 23], 1);
        esrc[p] = v & 0x7FFFFF;  // writes land in a 65KB L2-hot window
    }
}

// --------- input projection: h = relu(x @ W_in + b_in), fp32 + bf16 ---------

__global__ __launch_bounds__(256) void inproj_kernel(const float* __restrict__ x,
                                                     const float* __restrict__ W_in,
                                                     const float* __restrict__ b_in,
                                                     float* __restrict__ hA,
                                                     unsigned short* __restrict__ hAbf) {
    int n = blockIdx.x * 2 + (threadIdx.x >> 7);
    int j = threadIdx.x & 127;
    float acc = b_in[j];
#pragma unroll
    for (int f = 0; f < FI; ++f) acc += x[n * FI + f] * W_in[f * HD + j];
    acc = fmaxf(acc, 0.f);
    hA[n * HD + j] = acc;
    hAbf[n * HD + j] = f2bf(acc);
}

// -------- W pre-swizzle into MFMA B-fragment order (bf16), 3 mats fused -----

__global__ __launch_bounds__(64) void wprep_all(const float* __restrict__ W0,
                                                const float* __restrict__ W1,
                                                const float* __restrict__ W2,
                                                unsigned short* __restrict__ wf0,
                                                unsigned short* __restrict__ wf1,
                                                unsigned short* __restrict__ wf2) {
    const int blk = blockIdx.x;
    const float* W;
    unsigned short* Wf;
    int DO, rel;
    if (blk < 32) { W = W0; Wf = wf0; DO = 128; rel = blk; }
    else if (blk < 64) { W = W1; Wf = wf1; DO = 128; rel = blk - 32; }
    else { W = W2; Wf = wf2; DO = 64; rel = blk - 64; }
    const int lane = threadIdx.x;
    const int nt = rel >> 2;
    const int ks = rel & 3;
    short8 o;
#pragma unroll
    for (int j = 0; j < 8; ++j)
        o[j] = (short)f2bf(W[(ks * 32 + (lane >> 4) * 8 + j) * DO + nt * 16 + (lane & 15)]);
    *(short8*)(Wf + ((size_t)rel * 64 + lane) * 8) = o;
}

// -------- MFMA GEMM: B[N,DO](fp8) = (A[N,128](bf16) @ W) * dinv[row] --------
// Pre-scales each output row by dinv[row] so the gather is a pure row-sum.

template <int DO>
__global__ __launch_bounds__(256) void gemm_mfma(const unsigned short* __restrict__ A,
                                                 const unsigned short* __restrict__ Wf,
                                                 const float* __restrict__ dinv,
                                                 unsigned char* __restrict__ B) {
    constexpr int CT = DO / 64;  // col-tiles per wave: 2 (DO=128) or 1 (DO=64)
    const int tid = threadIdx.x;
    const int wave = tid >> 6;
    const int lane = tid & 63;
    const int n0 = blockIdx.x * 32;
    short8 bfrag[CT][4];
#pragma unroll
    for (int ct = 0; ct < CT; ++ct)
#pragma unroll
        for (int ks = 0; ks < 4; ++ks)
            bfrag[ct][ks] = *(const short8*)(Wf + ((size_t)(((wave * CT + ct) * 4 + ks) * 64) + lane) * 8);
#pragma unroll
    for (int rt = 0; rt < 2; ++rt) {
        const int arow = n0 + rt * 16 + (lane & 15);
        short8 afrag[4];
#pragma unroll
        for (int ks = 0; ks < 4; ++ks)
            afrag[ks] = *(const short8*)(A + (size_t)arow * HD + ks * 32 + ((lane >> 4) & 3) * 8);
        f32x4 acc[CT];
#pragma unroll
        for (int ct = 0; ct < CT; ++ct) acc[ct] = (f32x4){0.f, 0.f, 0.f, 0.f};
#pragma unroll
        for (int ks = 0; ks < 4; ++ks)
#pragma unroll
            for (int ct = 0; ct < CT; ++ct)
                acc[ct] = __builtin_amdgcn_mfma_f32_16x16x32_bf16(afrag[ks], bfrag[ct][ks], acc[ct], 0, 0, 0);
#pragma unroll
        for (int r = 0; r < 4; ++r) {
            const int orow = n0 + rt * 16 + (lane >> 4) * 4 + r;
            const float dv = dinv[orow];
#pragma unroll
            for (int ct = 0; ct < CT; ++ct) {
                const int ocol = (wave * CT + ct) * 16 + (lane & 15);
                B[(size_t)orow * DO + ocol] = f2fp8(acc[ct][r] * dv);
            }
        }
    }
}

// ---------- fused gather (pure row-sum) + self-loop + bias + BN (+relu/res) --
// R10: block (128 thr) per (dst node, column half). DOS = row stride of the
// fp8 table / residual arrays; W = DOS/2 columns handled by this block.
// blockIdx = 2n + h: even/odd blocks -> even/odd XCDs (round-robin heuristic)
// -> per-XCD table working set is the W-column slice only.
// hXW fp8 [N,DOS] PRE-SCALED by dinv[src]. thread t: col-group q=t&(CG-1)
// (8 cols, uint2), edge-group grp=t/CG. MUST launch with 2*NN blocks x 128.

template <int DOS, int W, bool RELU_RES>
__global__ __launch_bounds__(128) void gather_kernel(const unsigned char* __restrict__ hXW,
                                                     float* __restrict__ resOut,
                                                     unsigned short* __restrict__ resBf,
                                                     const int* __restrict__ rowstart,
                                                     const int* __restrict__ esrc,
                                                     const float* __restrict__ dinv,
                                                     const float* __restrict__ bias,
                                                     const float* __restrict__ g,
                                                     const float* __restrict__ be,
                                                     const float* __restrict__ m,
                                                     const float* __restrict__ v) {
    constexpr int CG = W / 8;     // 8 (W=64) or 4 (W=32) col-groups
    constexpr int NG = 128 / CG;  // 16 or 32 edge groups
    constexpr int QN = W / 4;     // output col-quads
    __shared__ int s_idx[128];
    __shared__ float sred[8][128];  // SoA partials
    const int n = blockIdx.x >> 1;
    const int colOff = (blockIdx.x & 1) * W;
    const int t = threadIdx.x;
    const int rs = rowstart[n];
    const int re = rowstart[n + 1];
    const float dn = dinv[n];
    const int q = t & (CG - 1);
    const int grp = t / CG;
    float4 a0l = {0.f, 0.f, 0.f, 0.f}, a0h = {0.f, 0.f, 0.f, 0.f};
    float4 a1l = {0.f, 0.f, 0.f, 0.f}, a1h = {0.f, 0.f, 0.f, 0.f};
    for (int base = rs; base < re; base += 128) {
        const int c = min(128, re - base);
        __syncthreads();
        if (t < c) s_idx[t] = esrc[base + t];
        __syncthreads();
        for (int j = grp; j < c; j += 2 * NG) {
            {
                const uint2 u = *(const uint2*)(hXW + (size_t)s_idx[j] * DOS + colOff + q * 8);
                const float2v l0 = __builtin_amdgcn_cvt_pk_f32_fp8(u.x, false);
                const float2v h0 = __builtin_amdgcn_cvt_pk_f32_fp8(u.x, true);
                const float2v l1 = __builtin_amdgcn_cvt_pk_f32_fp8(u.y, false);
                const float2v h1 = __builtin_amdgcn_cvt_pk_f32_fp8(u.y, true);
                a0l.x += l0.x; a0l.y += l0.y; a0l.z += h0.x; a0l.w += h0.y;
                a0h.x += l1.x; a0h.y += l1.y; a0h.z += h1.x; a0h.w += h1.y;
            }
            if (j + NG < c) {
                const uint2 u = *(const uint2*)(hXW + (size_t)s_idx[j + NG] * DOS + colOff + q * 8);
                const float2v l0 = __builtin_amdgcn_cvt_pk_f32_fp8(u.x, false);
                const float2v h0 = __builtin_amdgcn_cvt_pk_f32_fp8(u.x, true);
                const float2v l1 = __builtin_amdgcn_cvt_pk_f32_fp8(u.y, false);
                const float2v h1 = __builtin_amdgcn_cvt_pk_f32_fp8(u.y, true);
                a1l.x += l0.x; a1l.y += l0.y; a1l.z += h0.x; a1l.w += h0.y;
                a1h.x += l1.x; a1h.y += l1.y; a1h.z += h1.x; a1h.w += h1.y;
            }
        }
    }
    a0l.x += a1l.x; a0l.y += a1l.y; a0l.z += a1l.z; a0l.w += a1l.w;
    a0h.x += a1h.x; a0h.y += a1h.y; a0h.z += a1h.z; a0h.w += a1h.w;
    __syncthreads();
    sred[0][t] = a0l.x; sred[1][t] = a0l.y; sred[2][t] = a0l.z; sred[3][t] = a0l.w;
    sred[4][t] = a0h.x; sred[5][t] = a0h.y; sred[6][t] = a0h.z; sred[7][t] = a0h.w;
    __syncthreads();
    if (t < QN) {
        const int qq = t >> 1, h = t & 1;
        float4 sum = {0.f, 0.f, 0.f, 0.f};
#pragma unroll
        for (int k = 0; k < NG; ++k) {
            const int u = k * CG + qq;
            sum.x += sred[h * 4 + 0][u];
            sum.y += sred[h * 4 + 1][u];
            sum.z += sred[h * 4 + 2][u];
            sum.w += sred[h * 4 + 3][u];
        }
        // self-loop: stored row n is already dinv[n]*XW[n]
        const unsigned su = *(const unsigned*)(hXW + (size_t)n * DOS + colOff + t * 4);
        const float2v slo = __builtin_amdgcn_cvt_pk_f32_fp8(su, false);
        const float2v shi = __builtin_amdgcn_cvt_pk_f32_fp8(su, true);
        const float4 b4 = *(const float4*)(bias + colOff + t * 4);
        const float4 g4 = *(const float4*)(g + colOff + t * 4);
        const float4 be4 = *(const float4*)(be + colOff + t * 4);
        const float4 m4 = *(const float4*)(m + colOff + t * 4);
        const float4 v4 = *(const float4*)(v + colOff + t * 4);
        float4 val;
        val.x = (sum.x + slo.x) * dn + b4.x;
        val.y = (sum.y + slo.y) * dn + b4.y;
        val.z = (sum.z + shi.x) * dn + b4.z;
        val.w = (sum.w + shi.y) * dn + b4.w;
        val.x = (val.x - m4.x) * (g4.x * rsqrtf(v4.x + EPS)) + be4.x;
        val.y = (val.y - m4.y) * (g4.y * rsqrtf(v4.y + EPS)) + be4.y;
        val.z = (val.z - m4.z) * (g4.z * rsqrtf(v4.z + EPS)) + be4.z;
        val.w = (val.w - m4.w) * (g4.w * rsqrtf(v4.w + EPS)) + be4.w;
        float4* outp = (float4*)(resOut + (size_t)n * DOS + colOff + t * 4);
        if (RELU_RES) {
            const float4 r = *outp;
            val.x = fmaxf(val.x, 0.f) + r.x;
            val.y = fmaxf(val.y, 0.f) + r.y;
            val.z = fmaxf(val.z, 0.f) + r.z;
            val.w = fmaxf(val.w, 0.f) + r.w;
            ushort4 bf;
            bf.x = f2bf(val.x); bf.y = f2bf(val.y);
            bf.z = f2bf(val.z); bf.w = f2bf(val.w);
            *(ushort4*)(resBf + (size_t)n * DOS + colOff + t * 4) = bf;
        }
        *outp = val;
    }
}

// ---------------- launch ----------------

extern "C" void kernel_launch(void* const* d_in, const int* in_sizes, int n_in,
                              void* d_out, int out_size, void* d_ws, size_t ws_size,
                              hipStream_t stream) {
    const float* x    = (const float*)d_in[0];
    const int*   ei   = (const int*)d_in[1];
    const float* W_in = (const float*)d_in[2];
    const float* b_in = (const float*)d_in[3];
    const float* Wl[3] = {(const float*)d_in[4], (const float*)d_in[10], (const float*)d_in[16]};
    const float* bl[3] = {(const float*)d_in[5], (const float*)d_in[11], (const float*)d_in[17]};
    const float* gl[3] = {(const float*)d_in[6], (const float*)d_in[12], (const float*)d_in[18]};
    const float* bel[3] = {(const float*)d_in[7], (const float*)d_in[13], (const float*)d_in[19]};
    const float* ml[3] = {(const float*)d_in[8], (const float*)d_in[14], (const float*)d_in[20]};
    const float* vl[3] = {(const float*)d_in[9], (const float*)d_in[15], (const float*)d_in[21]};
    float* out = (float*)d_out;

    char* ws = (char*)d_ws;
    size_t off = 0;
    auto carve = [&](size_t bytes) {
        void* p = ws + off;
        off += (bytes + 255) & ~(size_t)255;
        return p;
    };
    int*   bcnt     = (int*)carve(NB * sizeof(int));
    int*   rowstart = (int*)carve((NN + 1) * sizeof(int));
    float* dinv     = (float*)carve(NN * sizeof(float));
    int*   esrc     = (int*)carve((size_t)NE * sizeof(int));
    float* hA       = (float*)carve((size_t)NN * HD * sizeof(float));
    unsigned short* hAbf = (unsigned short*)carve((size_t)NN * HD * sizeof(unsigned short));
    unsigned char* hB = (unsigned char*)carve((size_t)NN * HD);
    int*   ebin     = (int*)carve((size_t)NB * EMAX * sizeof(int));
    unsigned short* wf0 = (unsigned short*)carve((size_t)HD * HD * sizeof(unsigned short));
    unsigned short* wf1 = (unsigned short*)carve((size_t)HD * HD * sizeof(unsigned short));
    unsigned short* wf2 = (unsigned short*)carve((size_t)HD * DD * sizeof(unsigned short));
    (void)ws_size;

    hipMemsetAsync(bcnt, 0, NB * sizeof(int), stream);

    wprep_all<<<80, 64, 0, stream>>>(Wl[0], Wl[1], Wl[2], wf0, wf1, wf2);

    pA_bin<<<NBLK, 256, 0, stream>>>(ei, bcnt, ebin);
    p4_finalize<<<NB, 512, 0, stream>>>(bcnt, ebin, esrc, rowstart, dinv);

    inproj_kernel<<<NN / 2, 256, 0, stream>>>(x, W_in, b_in, hA, hAbf);

    // layer 0
    gemm_mfma<128><<<NN / 32, 256, 0, stream>>>(hAbf, wf0, dinv, hB);
    gather_kernel<128, 64, true><<<2 * NN, 128, 0, stream>>>(hB, hA, hAbf, rowstart, esrc, dinv,
                                                             bl[0], gl[0], bel[0], ml[0], vl[0]);
    // layer 1
    gemm_mfma<128><<<NN / 32, 256, 0, stream>>>(hAbf, wf1, dinv, hB);
    gather_kernel<128, 64, true><<<2 * NN, 128, 0, stream>>>(hB, hA, hAbf, rowstart, esrc, dinv,
                                                             bl[1], gl[1], bel[1], ml[1], vl[1]);
    // layer 2 (BN only, write d_out)
    gemm_mfma<64><<<NN / 32, 256, 0, stream>>>(hAbf, wf2, dinv, hB);
    gather_kernel<64, 32, false><<<2 * NN, 128, 0, stream>>>(hB, out, (unsigned short*)nullptr,
                                                             rowstart, esrc, dinv,
                                                             bl[2], gl[2], bel[2], ml[2], vl[2]);
}

// Round 2
// 555.483 us; speedup vs baseline: 1.2920x; 1.2920x over previous
//
#include <hip/hip_runtime.h>

// NuclideGNN: 3-layer GCN on MI355X.
// R9: hB rows pre-scaled by dinv[src] in GEMM epilogue -> gather is pure
//     row-sum; p1+p3 fused into one LDS-staged pass.
// R10 (REVERTED): column-split gather -- falsified: 128B-line granularity
//     means per-XCD byte footprint doesn't shrink; requests doubled.
// R11: wave-per-node gather. One 64-lane wave per node, no LDS, no barriers:
//     edge rows read by 16-lane (CG) groups as uint2 (full-line coalesced),
//     esrc read directly (L2-hot, same-addr lanes merge), partial reduction
//     via register butterfly (__shfl_xor), epilogue in lanes 0..CG-1.
//     Predicted: bank conflicts 3.2M->0, occupancy 71->85+%, dur 84->~65us.

#define NN 100000
#define NE 3200000
#define FI 7
#define HD 128
#define DD 64
#define EPS 1e-5f
#define NB 196                        // buckets of 512 dst nodes (dst>>9)
#define EPB 8192                      // edges per pA block (256 thr x 32)
#define NBLK ((NE + EPB - 1) / EPB)   // 391
#define EMAX 20000                    // fixed ebin window per bucket (max ~16.7k)

typedef float float2v __attribute__((ext_vector_type(2)));
typedef short short8 __attribute__((ext_vector_type(8)));
typedef float f32x4 __attribute__((ext_vector_type(4)));

__device__ __forceinline__ unsigned char f2fp8(float f) {
    return (unsigned char)(__builtin_amdgcn_cvt_pk_fp8_f32(f, f, 0, false) & 0xFF);
}
__device__ __forceinline__ unsigned short f2bf(float f) {
    unsigned u = __float_as_uint(f);
    u += 0x7FFF + ((u >> 16) & 1);  // RNE
    return (unsigned short)(u >> 16);
}

// ---------------- CSR build ----------------

__global__ __launch_bounds__(256) void pA_bin(const int* __restrict__ ei,
                                              int* __restrict__ bcnt,
                                              int* __restrict__ ebin) {
    __shared__ int sdst[EPB];   // 32 KB
    __shared__ int hcur[NB];
    const int t = threadIdx.x;
    for (int b = t; b < NB; b += 256) hcur[b] = 0;
    __syncthreads();
    const int base = blockIdx.x * EPB;
    const int cnt = min(EPB, NE - base);
    for (int i = t; i < cnt; i += 256) {
        int d = ei[NE + base + i];
        sdst[i] = d;
        atomicAdd(&hcur[d >> 9], 1);
    }
    __syncthreads();
    for (int b = t; b < NB; b += 256) {
        int c = hcur[b];
        hcur[b] = (c ? atomicAdd(&bcnt[b], c) : 0) + b * EMAX;
    }
    __syncthreads();
    for (int i = t; i < cnt; i += 256) {
        int s = ei[base + i];
        int d = sdst[i];
        int p = atomicAdd(&hcur[d >> 9], 1);
        ebin[p] = ((d & 511) << 23) | s;
    }
}

// p4: local bucket scan (dense esrc offsets) + per-bucket hist/scan/scatter.
__global__ __launch_bounds__(512) void p4_finalize(const int* __restrict__ bcnt,
                                                   const int* __restrict__ ebin,
                                                   int* __restrict__ esrc,
                                                   int* __restrict__ rowstart,
                                                   float* __restrict__ dinv) {
    __shared__ int sh[256];  // bucket-count scan
    __shared__ int lh[512];  // local degree
    __shared__ int sc[512];  // scan buffer
    __shared__ int lc[512];  // local cursor
    const int t = threadIdx.x;
    const int b = blockIdx.x;
    if (t < 256) sh[t] = (t < NB) ? bcnt[t] : 0;
    __syncthreads();
    for (int off = 1; off < 256; off <<= 1) {
        int v = (t < 256 && t >= off) ? sh[t - off] : 0;
        __syncthreads();
        if (t < 256) sh[t] += v;
        __syncthreads();
    }
    const int ecnt = bcnt[b];
    const int ebase = sh[b] - ecnt;   // dense esrc base for this bucket
    const int rbase = b * EMAX;       // padded ebin read base
    const int n0 = b << 9;
    lh[t] = 0;
    __syncthreads();
    for (int i = t; i < ecnt; i += 512)
        atomicAdd(&lh[((unsigned)ebin[rbase + i]) >> 23], 1);
    __syncthreads();
    const int c = lh[t];
    sc[t] = c;
    __syncthreads();
    for (int off = 1; off < 512; off <<= 1) {
        int v = (t >= off) ? sc[t - off] : 0;
        __syncthreads();
        sc[t] += v;
        __syncthreads();
    }
    const int excl = ebase + sc[t] - c;  // global rowstart for node n0+t
    lc[t] = excl;
    const int node = n0 + t;
    if (node < NN) {
        rowstart[node] = excl;
        dinv[node] = rsqrtf((float)c + 1.0f);  // deg includes self-loop
    }
    if (b == NB - 1 && t == 0) rowstart[NN] = NE;
    __syncthreads();
    for (int i = t; i < ecnt; i += 512) {
        int v = ebin[rbase + i];
        int p = atomicAdd(&lc[((unsigned)v) >> 23], 1);
        esrc[p] = v & 0x7FFFFF;  // writes land in a 65KB L2-hot window
    }
}

// --------- input projection: h = relu(x @ W_in + b_in), fp32 + bf16 ---------

__global__ __launch_bounds__(256) void inproj_kernel(const float* __restrict__ x,
                                                     const float* __restrict__ W_in,
                                                     const float* __restrict__ b_in,
                                                     float* __restrict__ hA,
                                                     unsigned short* __restrict__ hAbf) {
    int n = blockIdx.x * 2 + (threadIdx.x >> 7);
    int j = threadIdx.x & 127;
    float acc = b_in[j];
#pragma unroll
    for (int f = 0; f < FI; ++f) acc += x[n * FI + f] * W_in[f * HD + j];
    acc = fmaxf(acc, 0.f);
    hA[n * HD + j] = acc;
    hAbf[n * HD + j] = f2bf(acc);
}

// -------- W pre-swizzle into MFMA B-fragment order (bf16), 3 mats fused -----

__global__ __launch_bounds__(64) void wprep_all(const float* __restrict__ W0,
                                                const float* __restrict__ W1,
                                                const float* __restrict__ W2,
                                                unsigned short* __restrict__ wf0,
                                                unsigned short* __restrict__ wf1,
                                                unsigned short* __restrict__ wf2) {
    const int blk = blockIdx.x;
    const float* W;
    unsigned short* Wf;
    int DO, rel;
    if (blk < 32) { W = W0; Wf = wf0; DO = 128; rel = blk; }
    else if (blk < 64) { W = W1; Wf = wf1; DO = 128; rel = blk - 32; }
    else { W = W2; Wf = wf2; DO = 64; rel = blk - 64; }
    const int lane = threadIdx.x;
    const int nt = rel >> 2;
    const int ks = rel & 3;
    short8 o;
#pragma unroll
    for (int j = 0; j < 8; ++j)
        o[j] = (short)f2bf(W[(ks * 32 + (lane >> 4) * 8 + j) * DO + nt * 16 + (lane & 15)]);
    *(short8*)(Wf + ((size_t)rel * 64 + lane) * 8) = o;
}

// -------- MFMA GEMM: B[N,DO](fp8) = (A[N,128](bf16) @ W) * dinv[row] --------

template <int DO>
__global__ __launch_bounds__(256) void gemm_mfma(const unsigned short* __restrict__ A,
                                                 const unsigned short* __restrict__ Wf,
                                                 const float* __restrict__ dinv,
                                                 unsigned char* __restrict__ B) {
    constexpr int CT = DO / 64;  // col-tiles per wave: 2 (DO=128) or 1 (DO=64)
    const int tid = threadIdx.x;
    const int wave = tid >> 6;
    const int lane = tid & 63;
    const int n0 = blockIdx.x * 32;
    short8 bfrag[CT][4];
#pragma unroll
    for (int ct = 0; ct < CT; ++ct)
#pragma unroll
        for (int ks = 0; ks < 4; ++ks)
            bfrag[ct][ks] = *(const short8*)(Wf + ((size_t)(((wave * CT + ct) * 4 + ks) * 64) + lane) * 8);
#pragma unroll
    for (int rt = 0; rt < 2; ++rt) {
        const int arow = n0 + rt * 16 + (lane & 15);
        short8 afrag[4];
#pragma unroll
        for (int ks = 0; ks < 4; ++ks)
            afrag[ks] = *(const short8*)(A + (size_t)arow * HD + ks * 32 + ((lane >> 4) & 3) * 8);
        f32x4 acc[CT];
#pragma unroll
        for (int ct = 0; ct < CT; ++ct) acc[ct] = (f32x4){0.f, 0.f, 0.f, 0.f};
#pragma unroll
        for (int ks = 0; ks < 4; ++ks)
#pragma unroll
            for (int ct = 0; ct < CT; ++ct)
                acc[ct] = __builtin_amdgcn_mfma_f32_16x16x32_bf16(afrag[ks], bfrag[ct][ks], acc[ct], 0, 0, 0);
#pragma unroll
        for (int r = 0; r < 4; ++r) {
            const int orow = n0 + rt * 16 + (lane >> 4) * 4 + r;
            const float dv = dinv[orow];
#pragma unroll
            for (int ct = 0; ct < CT; ++ct) {
                const int ocol = (wave * CT + ct) * 16 + (lane & 15);
                B[(size_t)orow * DO + ocol] = f2fp8(acc[ct][r] * dv);
            }
        }
    }
}

// ---------- R11 wave-per-node gather + self-loop + bias + BN (+relu/res) ----
// One 64-lane wave per node. CG = DOS/8 lanes share each edge-row uint2 read;
// G = 64/CG edge groups stream independent edges (2-deep unrolled).
// No LDS, no __syncthreads. Butterfly shfl_xor all-reduce across groups.
// Launch: <<<NN/4, 256>>> (4 waves = 4 nodes per block).

template <int DOS, bool RELU_RES>
__global__ __launch_bounds__(256) void gather_wave(const unsigned char* __restrict__ hXW,
                                                   float* __restrict__ resOut,
                                                   unsigned short* __restrict__ resBf,
                                                   const int* __restrict__ rowstart,
                                                   const int* __restrict__ esrc,
                                                   const float* __restrict__ dinv,
                                                   const float* __restrict__ bias,
                                                   const float* __restrict__ g,
                                                   const float* __restrict__ be,
                                                   const float* __restrict__ m,
                                                   const float* __restrict__ v) {
    constexpr int CG = DOS / 8;   // lanes per edge row: 16 (DOS=128) / 8 (DOS=64)
    constexpr int G = 64 / CG;    // edge groups per wave: 4 / 8
    const int t = threadIdx.x;
    const int lane = t & 63;
    const int n = blockIdx.x * 4 + (t >> 6);
    const int rs = rowstart[n];
    const int re = rowstart[n + 1];
    const int q = lane & (CG - 1);
    const int grp = lane / CG;
    float4 al = {0.f, 0.f, 0.f, 0.f}, ah = {0.f, 0.f, 0.f, 0.f};
    float4 bl = {0.f, 0.f, 0.f, 0.f}, bh = {0.f, 0.f, 0.f, 0.f};
    for (int j = rs + grp; j < re; j += 2 * G) {
        {
            const int idx = esrc[j];
            const uint2 u = *(const uint2*)(hXW + (size_t)idx * DOS + q * 8);
            const float2v l0 = __builtin_amdgcn_cvt_pk_f32_fp8(u.x, false);
            const float2v h0 = __builtin_amdgcn_cvt_pk_f32_fp8(u.x, true);
            const float2v l1 = __builtin_amdgcn_cvt_pk_f32_fp8(u.y, false);
            const float2v h1 = __builtin_amdgcn_cvt_pk_f32_fp8(u.y, true);
            al.x += l0.x; al.y += l0.y; al.z += h0.x; al.w += h0.y;
            ah.x += l1.x; ah.y += l1.y; ah.z += h1.x; ah.w += h1.y;
        }
        if (j + G < re) {
            const int idx = esrc[j + G];
            const uint2 u = *(const uint2*)(hXW + (size_t)idx * DOS + q * 8);
            const float2v l0 = __builtin_amdgcn_cvt_pk_f32_fp8(u.x, false);
            const float2v h0 = __builtin_amdgcn_cvt_pk_f32_fp8(u.x, true);
            const float2v l1 = __builtin_amdgcn_cvt_pk_f32_fp8(u.y, false);
            const float2v h1 = __builtin_amdgcn_cvt_pk_f32_fp8(u.y, true);
            bl.x += l0.x; bl.y += l0.y; bl.z += h0.x; bl.w += h0.y;
            bh.x += l1.x; bh.y += l1.y; bh.z += h1.x; bh.w += h1.y;
        }
    }
    al.x += bl.x; al.y += bl.y; al.z += bl.z; al.w += bl.w;
    ah.x += bh.x; ah.y += bh.y; ah.z += bh.z; ah.w += bh.w;
    // butterfly all-reduce across the G edge-groups (masks CG..32)
#pragma unroll
    for (int mask = CG; mask < 64; mask <<= 1) {
        al.x += __shfl_xor(al.x, mask); al.y += __shfl_xor(al.y, mask);
        al.z += __shfl_xor(al.z, mask); al.w += __shfl_xor(al.w, mask);
        ah.x += __shfl_xor(ah.x, mask); ah.y += __shfl_xor(ah.y, mask);
        ah.z += __shfl_xor(ah.z, mask); ah.w += __shfl_xor(ah.w, mask);
    }
    if (lane < CG) {
        const float dn = dinv[n];
        // self-loop: stored row n is already dinv[n]*XW[n]
        const uint2 su = *(const uint2*)(hXW + (size_t)n * DOS + q * 8);
        const float2v s0l = __builtin_amdgcn_cvt_pk_f32_fp8(su.x, false);
        const float2v s0h = __builtin_amdgcn_cvt_pk_f32_fp8(su.x, true);
        const float2v s1l = __builtin_amdgcn_cvt_pk_f32_fp8(su.y, false);
        const float2v s1h = __builtin_amdgcn_cvt_pk_f32_fp8(su.y, true);
        const int c0 = q * 8;
        const float4 b4a = *(const float4*)(bias + c0);
        const float4 b4b = *(const float4*)(bias + c0 + 4);
        const float4 g4a = *(const float4*)(g + c0);
        const float4 g4b = *(const float4*)(g + c0 + 4);
        const float4 e4a = *(const float4*)(be + c0);
        const float4 e4b = *(const float4*)(be + c0 + 4);
        const float4 m4a = *(const float4*)(m + c0);
        const float4 m4b = *(const float4*)(m + c0 + 4);
        const float4 v4a = *(const float4*)(v + c0);
        const float4 v4b = *(const float4*)(v + c0 + 4);
        float4 o1, o2;
        o1.x = (al.x + s0l.x) * dn + b4a.x;
        o1.y = (al.y + s0l.y) * dn + b4a.y;
        o1.z = (al.z + s0h.x) * dn + b4a.z;
        o1.w = (al.w + s0h.y) * dn + b4a.w;
        o2.x = (ah.x + s1l.x) * dn + b4b.x;
        o2.y = (ah.y + s1l.y) * dn + b4b.y;
        o2.z = (ah.z + s1h.x) * dn + b4b.z;
        o2.w = (ah.w + s1h.y) * dn + b4b.w;
        o1.x = (o1.x - m4a.x) * (g4a.x * rsqrtf(v4a.x + EPS)) + e4a.x;
        o1.y = (o1.y - m4a.y) * (g4a.y * rsqrtf(v4a.y + EPS)) + e4a.y;
        o1.z = (o1.z - m4a.z) * (g4a.z * rsqrtf(v4a.z + EPS)) + e4a.z;
        o1.w = (o1.w - m4a.w) * (g4a.w * rsqrtf(v4a.w + EPS)) + e4a.w;
        o2.x = (o2.x - m4b.x) * (g4b.x * rsqrtf(v4b.x + EPS)) + e4b.x;
        o2.y = (o2.y - m4b.y) * (g4b.y * rsqrtf(v4b.y + EPS)) + e4b.y;
        o2.z = (o2.z - m4b.z) * (g4b.z * rsqrtf(v4b.z + EPS)) + e4b.z;
        o2.w = (o2.w - m4b.w) * (g4b.w * rsqrtf(v4b.w + EPS)) + e4b.w;
        float* outp = resOut + (size_t)n * DOS + c0;
        if (RELU_RES) {
            const float4 r1 = *(const float4*)outp;
            const float4 r2 = *(const float4*)(outp + 4);
            o1.x = fmaxf(o1.x, 0.f) + r1.x;
            o1.y = fmaxf(o1.y, 0.f) + r1.y;
            o1.z = fmaxf(o1.z, 0.f) + r1.z;
            o1.w = fmaxf(o1.w, 0.f) + r1.w;
            o2.x = fmaxf(o2.x, 0.f) + r2.x;
            o2.y = fmaxf(o2.y, 0.f) + r2.y;
            o2.z = fmaxf(o2.z, 0.f) + r2.z;
            o2.w = fmaxf(o2.w, 0.f) + r2.w;
            short8 bf;
            bf[0] = (short)f2bf(o1.x); bf[1] = (short)f2bf(o1.y);
            bf[2] = (short)f2bf(o1.z); bf[3] = (short)f2bf(o1.w);
            bf[4] = (short)f2bf(o2.x); bf[5] = (short)f2bf(o2.y);
            bf[6] = (short)f2bf(o2.z); bf[7] = (short)f2bf(o2.w);
            *(short8*)(resBf + (size_t)n * DOS + c0) = bf;
        }
        *(float4*)outp = o1;
        *(float4*)(outp + 4) = o2;
    }
}

// ---------------- launch ----------------

extern "C" void kernel_launch(void* const* d_in, const int* in_sizes, int n_in,
                              void* d_out, int out_size, void* d_ws, size_t ws_size,
                              hipStream_t stream) {
    const float* x    = (const float*)d_in[0];
    const int*   ei   = (const int*)d_in[1];
    const float* W_in = (const float*)d_in[2];
    const float* b_in = (const float*)d_in[3];
    const float* Wl[3] = {(const float*)d_in[4], (const float*)d_in[10], (const float*)d_in[16]};
    const float* bl[3] = {(const float*)d_in[5], (const float*)d_in[11], (const float*)d_in[17]};
    const float* gl[3] = {(const float*)d_in[6], (const float*)d_in[12], (const float*)d_in[18]};
    const float* bel[3] = {(const float*)d_in[7], (const float*)d_in[13], (const float*)d_in[19]};
    const float* ml[3] = {(const float*)d_in[8], (const float*)d_in[14], (const float*)d_in[20]};
    const float* vl[3] = {(const float*)d_in[9], (const float*)d_in[15], (const float*)d_in[21]};
    float* out = (float*)d_out;

    char* ws = (char*)d_ws;
    size_t off = 0;
    auto carve = [&](size_t bytes) {
        void* p = ws + off;
        off += (bytes + 255) & ~(size_t)255;
        return p;
    };
    int*   bcnt     = (int*)carve(NB * sizeof(int));
    int*   rowstart = (int*)carve((NN + 1) * sizeof(int));
    float* dinv     = (float*)carve(NN * sizeof(float));
    int*   esrc     = (int*)carve((size_t)NE * sizeof(int));
    float* hA       = (float*)carve((size_t)NN * HD * sizeof(float));
    unsigned short* hAbf = (unsigned short*)carve((size_t)NN * HD * sizeof(unsigned short));
    unsigned char* hB = (unsigned char*)carve((size_t)NN * HD);
    int*   ebin     = (int*)carve((size_t)NB * EMAX * sizeof(int));
    unsigned short* wf0 = (unsigned short*)carve((size_t)HD * HD * sizeof(unsigned short));
    unsigned short* wf1 = (unsigned short*)carve((size_t)HD * HD * sizeof(unsigned short));
    unsigned short* wf2 = (unsigned short*)carve((size_t)HD * DD * sizeof(unsigned short));
    (void)ws_size;

    hipMemsetAsync(bcnt, 0, NB * sizeof(int), stream);

    wprep_all<<<80, 64, 0, stream>>>(Wl[0], Wl[1], Wl[2], wf0, wf1, wf2);

    pA_bin<<<NBLK, 256, 0, stream>>>(ei, bcnt, ebin);
    p4_finalize<<<NB, 512, 0, stream>>>(bcnt, ebin, esrc, rowstart, dinv);

    inproj_kernel<<<NN / 2, 256, 0, stream>>>(x, W_in, b_in, hA, hAbf);

    // layer 0
    gemm_mfma<128><<<NN / 32, 256, 0, stream>>>(hAbf, wf0, dinv, hB);
    gather_wave<128, true><<<NN / 4, 256, 0, stream>>>(hB, hA, hAbf, rowstart, esrc, dinv,
                                                       bl[0], gl[0], bel[0], ml[0], vl[0]);
    // layer 1
    gemm_mfma<128><<<NN / 32, 256, 0, stream>>>(hAbf, wf1, dinv, hB);
    gather_wave<128, true><<<NN / 4, 256, 0, stream>>>(hB, hA, hAbf, rowstart, esrc, dinv,
                                                       bl[1], gl[1], bel[1], ml[1], vl[1]);
    // layer 2 (BN only, write d_out)
    gemm_mfma<64><<<NN / 32, 256, 0, stream>>>(hAbf, wf2, dinv, hB);
    gather_wave<64, false><<<NN / 4, 256, 0, stream>>>(hB, out, (unsigned short*)nullptr,
                                                       rowstart, esrc, dinv,
                                                       bl[2], gl[2], bel[2], ml[2], vl[2]);
}

// Round 3
// 546.762 us; speedup vs baseline: 1.3126x; 1.0160x over previous
//
#include <hip/hip_runtime.h>

// NuclideGNN: 3-layer GCN on MI355X.
// R9: hB rows pre-scaled by dinv[src] in GEMM epilogue -> gather is pure
//     row-sum; p1+p3 fused into one LDS-staged pass.
// R10 (REVERTED): column-split gather -- 128B-line granularity means per-XCD
//     footprint doesn't shrink; requests doubled.
// R11 (REVERTED): wave-per-node gather -- halved total threads -> halved MLP;
//     BW 3.36->2.52 TB/s. Gather is latency/MLP-bound.
// R12: R9 block-per-node structure + 4-deep edge MLP. Each edge-group owns a
//     contiguous 4-edge chunk: 4 esrc loads (1 line, broadcast) + 4 row loads
//     in flight; no per-tile barriers (s_idx staging dropped). Typical node
//     (deg~32) = one iteration. Predicted: gather 83.7->~64us, BW ->4.5TB/s.

#define NN 100000
#define NE 3200000
#define FI 7
#define HD 128
#define DD 64
#define EPS 1e-5f
#define NB 196                        // buckets of 512 dst nodes (dst>>9)
#define EPB 8192                      // edges per pA block (256 thr x 32)
#define NBLK ((NE + EPB - 1) / EPB)   // 391
#define EMAX 20000                    // fixed ebin window per bucket (max ~16.7k)

typedef float float2v __attribute__((ext_vector_type(2)));
typedef short short8 __attribute__((ext_vector_type(8)));
typedef float f32x4 __attribute__((ext_vector_type(4)));

__device__ __forceinline__ unsigned char f2fp8(float f) {
    return (unsigned char)(__builtin_amdgcn_cvt_pk_fp8_f32(f, f, 0, false) & 0xFF);
}
__device__ __forceinline__ unsigned short f2bf(float f) {
    unsigned u = __float_as_uint(f);
    u += 0x7FFF + ((u >> 16) & 1);  // RNE
    return (unsigned short)(u >> 16);
}

// ---------------- CSR build ----------------

__global__ __launch_bounds__(256) void pA_bin(const int* __restrict__ ei,
                                              int* __restrict__ bcnt,
                                              int* __restrict__ ebin) {
    __shared__ int sdst[EPB];   // 32 KB
    __shared__ int hcur[NB];
    const int t = threadIdx.x;
    for (int b = t; b < NB; b += 256) hcur[b] = 0;
    __syncthreads();
    const int base = blockIdx.x * EPB;
    const int cnt = min(EPB, NE - base);
    for (int i = t; i < cnt; i += 256) {
        int d = ei[NE + base + i];
        sdst[i] = d;
        atomicAdd(&hcur[d >> 9], 1);
    }
    __syncthreads();
    for (int b = t; b < NB; b += 256) {
        int c = hcur[b];
        hcur[b] = (c ? atomicAdd(&bcnt[b], c) : 0) + b * EMAX;
    }
    __syncthreads();
    for (int i = t; i < cnt; i += 256) {
        int s = ei[base + i];
        int d = sdst[i];
        int p = atomicAdd(&hcur[d >> 9], 1);
        ebin[p] = ((d & 511) << 23) | s;
    }
}

// p4: local bucket scan (dense esrc offsets) + per-bucket hist/scan/scatter.
__global__ __launch_bounds__(512) void p4_finalize(const int* __restrict__ bcnt,
                                                   const int* __restrict__ ebin,
                                                   int* __restrict__ esrc,
                                                   int* __restrict__ rowstart,
                                                   float* __restrict__ dinv) {
    __shared__ int sh[256];  // bucket-count scan
    __shared__ int lh[512];  // local degree
    __shared__ int sc[512];  // scan buffer
    __shared__ int lc[512];  // local cursor
    const int t = threadIdx.x;
    const int b = blockIdx.x;
    if (t < 256) sh[t] = (t < NB) ? bcnt[t] : 0;
    __syncthreads();
    for (int off = 1; off < 256; off <<= 1) {
        int v = (t < 256 && t >= off) ? sh[t - off] : 0;
        __syncthreads();
        if (t < 256) sh[t] += v;
        __syncthreads();
    }
    const int ecnt = bcnt[b];
    const int ebase = sh[b] - ecnt;   // dense esrc base for this bucket
    const int rbase = b * EMAX;       // padded ebin read base
    const int n0 = b << 9;
    lh[t] = 0;
    __syncthreads();
    for (int i = t; i < ecnt; i += 512)
        atomicAdd(&lh[((unsigned)ebin[rbase + i]) >> 23], 1);
    __syncthreads();
    const int c = lh[t];
    sc[t] = c;
    __syncthreads();
    for (int off = 1; off < 512; off <<= 1) {
        int v = (t >= off) ? sc[t - off] : 0;
        __syncthreads();
        sc[t] += v;
        __syncthreads();
    }
    const int excl = ebase + sc[t] - c;  // global rowstart for node n0+t
    lc[t] = excl;
    const int node = n0 + t;
    if (node < NN) {
        rowstart[node] = excl;
        dinv[node] = rsqrtf((float)c + 1.0f);  // deg includes self-loop
    }
    if (b == NB - 1 && t == 0) rowstart[NN] = NE;
    __syncthreads();
    for (int i = t; i < ecnt; i += 512) {
        int v = ebin[rbase + i];
        int p = atomicAdd(&lc[((unsigned)v) >> 23], 1);
        esrc[p] = v & 0x7FFFFF;  // writes land in a 65KB L2-hot window
    }
}

// --------- input projection: h = relu(x @ W_in + b_in), fp32 + bf16 ---------

__global__ __launch_bounds__(256) void inproj_kernel(const float* __restrict__ x,
                                                     const float* __restrict__ W_in,
                                                     const float* __restrict__ b_in,
                                                     float* __restrict__ hA,
                                                     unsigned short* __restrict__ hAbf) {
    int n = blockIdx.x * 2 + (threadIdx.x >> 7);
    int j = threadIdx.x & 127;
    float acc = b_in[j];
#pragma unroll
    for (int f = 0; f < FI; ++f) acc += x[n * FI + f] * W_in[f * HD + j];
    acc = fmaxf(acc, 0.f);
    hA[n * HD + j] = acc;
    hAbf[n * HD + j] = f2bf(acc);
}

// -------- W pre-swizzle into MFMA B-fragment order (bf16), 3 mats fused -----

__global__ __launch_bounds__(64) void wprep_all(const float* __restrict__ W0,
                                                const float* __restrict__ W1,
                                                const float* __restrict__ W2,
                                                unsigned short* __restrict__ wf0,
                                                unsigned short* __restrict__ wf1,
                                                unsigned short* __restrict__ wf2) {
    const int blk = blockIdx.x;
    const float* W;
    unsigned short* Wf;
    int DO, rel;
    if (blk < 32) { W = W0; Wf = wf0; DO = 128; rel = blk; }
    else if (blk < 64) { W = W1; Wf = wf1; DO = 128; rel = blk - 32; }
    else { W = W2; Wf = wf2; DO = 64; rel = blk - 64; }
    const int lane = threadIdx.x;
    const int nt = rel >> 2;
    const int ks = rel & 3;
    short8 o;
#pragma unroll
    for (int j = 0; j < 8; ++j)
        o[j] = (short)f2bf(W[(ks * 32 + (lane >> 4) * 8 + j) * DO + nt * 16 + (lane & 15)]);
    *(short8*)(Wf + ((size_t)rel * 64 + lane) * 8) = o;
}

// -------- MFMA GEMM: B[N,DO](fp8) = (A[N,128](bf16) @ W) * dinv[row] --------

template <int DO>
__global__ __launch_bounds__(256) void gemm_mfma(const unsigned short* __restrict__ A,
                                                 const unsigned short* __restrict__ Wf,
                                                 const float* __restrict__ dinv,
                                                 unsigned char* __restrict__ B) {
    constexpr int CT = DO / 64;  // col-tiles per wave: 2 (DO=128) or 1 (DO=64)
    const int tid = threadIdx.x;
    const int wave = tid >> 6;
    const int lane = tid & 63;
    const int n0 = blockIdx.x * 32;
    short8 bfrag[CT][4];
#pragma unroll
    for (int ct = 0; ct < CT; ++ct)
#pragma unroll
        for (int ks = 0; ks < 4; ++ks)
            bfrag[ct][ks] = *(const short8*)(Wf + ((size_t)(((wave * CT + ct) * 4 + ks) * 64) + lane) * 8);
#pragma unroll
    for (int rt = 0; rt < 2; ++rt) {
        const int arow = n0 + rt * 16 + (lane & 15);
        short8 afrag[4];
#pragma unroll
        for (int ks = 0; ks < 4; ++ks)
            afrag[ks] = *(const short8*)(A + (size_t)arow * HD + ks * 32 + ((lane >> 4) & 3) * 8);
        f32x4 acc[CT];
#pragma unroll
        for (int ct = 0; ct < CT; ++ct) acc[ct] = (f32x4){0.f, 0.f, 0.f, 0.f};
#pragma unroll
        for (int ks = 0; ks < 4; ++ks)
#pragma unroll
            for (int ct = 0; ct < CT; ++ct)
                acc[ct] = __builtin_amdgcn_mfma_f32_16x16x32_bf16(afrag[ks], bfrag[ct][ks], acc[ct], 0, 0, 0);
#pragma unroll
        for (int r = 0; r < 4; ++r) {
            const int orow = n0 + rt * 16 + (lane >> 4) * 4 + r;
            const float dv = dinv[orow];
#pragma unroll
            for (int ct = 0; ct < CT; ++ct) {
                const int ocol = (wave * CT + ct) * 16 + (lane & 15);
                B[(size_t)orow * DO + ocol] = f2fp8(acc[ct][r] * dv);
            }
        }
    }
}

// ---------- R12 gather: block-per-node, 4-deep edge MLP, no staging ---------
// 128 threads per node. CG = DOS/8 lanes per row (q), NG = 128/CG edge groups.
// Group grp owns contiguous 4-edge chunks [rs+grp*4 + k*NG*4, +4).
// Fast path: 4 esrc loads (one line, broadcast across group) + 4 row uint2
// loads in flight -> 32 rows outstanding per node. sred epilogue as R9.

template <int DOS, bool RELU_RES>
__global__ __launch_bounds__(128) void gather_kernel(const unsigned char* __restrict__ hXW,
                                                     float* __restrict__ resOut,
                                                     unsigned short* __restrict__ resBf,
                                                     const int* __restrict__ rowstart,
                                                     const int* __restrict__ esrc,
                                                     const float* __restrict__ dinv,
                                                     const float* __restrict__ bias,
                                                     const float* __restrict__ g,
                                                     const float* __restrict__ be,
                                                     const float* __restrict__ m,
                                                     const float* __restrict__ v) {
    constexpr int CG = DOS / 8;   // 16 (DOS=128) or 8 (DOS=64)
    constexpr int NG = 128 / CG;  // 8 or 16 edge groups
    constexpr int QN = DOS / 4;   // output col-quads
    __shared__ float sred[8][128];
    const int n = blockIdx.x;
    const int t = threadIdx.x;
    const int rs = rowstart[n];
    const int re = rowstart[n + 1];
    const int q = t & (CG - 1);
    const int grp = t / CG;
    float4 a0l = {0.f, 0.f, 0.f, 0.f}, a0h = {0.f, 0.f, 0.f, 0.f};
    float4 a1l = {0.f, 0.f, 0.f, 0.f}, a1h = {0.f, 0.f, 0.f, 0.f};
    for (int base = rs + grp * 4; base < re; base += NG * 4) {
        if (base + 4 <= re) {
            const int i0 = esrc[base + 0];
            const int i1 = esrc[base + 1];
            const int i2 = esrc[base + 2];
            const int i3 = esrc[base + 3];
            const uint2 u0 = *(const uint2*)(hXW + (size_t)i0 * DOS + q * 8);
            const uint2 u1 = *(const uint2*)(hXW + (size_t)i1 * DOS + q * 8);
            const uint2 u2 = *(const uint2*)(hXW + (size_t)i2 * DOS + q * 8);
            const uint2 u3 = *(const uint2*)(hXW + (size_t)i3 * DOS + q * 8);
            {
                const float2v l0 = __builtin_amdgcn_cvt_pk_f32_fp8(u0.x, false);
                const float2v h0 = __builtin_amdgcn_cvt_pk_f32_fp8(u0.x, true);
                const float2v l1 = __builtin_amdgcn_cvt_pk_f32_fp8(u0.y, false);
                const float2v h1 = __builtin_amdgcn_cvt_pk_f32_fp8(u0.y, true);
                a0l.x += l0.x; a0l.y += l0.y; a0l.z += h0.x; a0l.w += h0.y;
                a0h.x += l1.x; a0h.y += l1.y; a0h.z += h1.x; a0h.w += h1.y;
            }
            {
                const float2v l0 = __builtin_amdgcn_cvt_pk_f32_fp8(u1.x, false);
                const float2v h0 = __builtin_amdgcn_cvt_pk_f32_fp8(u1.x, true);
                const float2v l1 = __builtin_amdgcn_cvt_pk_f32_fp8(u1.y, false);
                const float2v h1 = __builtin_amdgcn_cvt_pk_f32_fp8(u1.y, true);
                a1l.x += l0.x; a1l.y += l0.y; a1l.z += h0.x; a1l.w += h0.y;
                a1h.x += l1.x; a1h.y += l1.y; a1h.z += h1.x; a1h.w += h1.y;
            }
            {
                const float2v l0 = __builtin_amdgcn_cvt_pk_f32_fp8(u2.x, false);
                const float2v h0 = __builtin_amdgcn_cvt_pk_f32_fp8(u2.x, true);
                const float2v l1 = __builtin_amdgcn_cvt_pk_f32_fp8(u2.y, false);
                const float2v h1 = __builtin_amdgcn_cvt_pk_f32_fp8(u2.y, true);
                a0l.x += l0.x; a0l.y += l0.y; a0l.z += h0.x; a0l.w += h0.y;
                a0h.x += l1.x; a0h.y += l1.y; a0h.z += h1.x; a0h.w += h1.y;
            }
            {
                const float2v l0 = __builtin_amdgcn_cvt_pk_f32_fp8(u3.x, false);
                const float2v h0 = __builtin_amdgcn_cvt_pk_f32_fp8(u3.x, true);
                const float2v l1 = __builtin_amdgcn_cvt_pk_f32_fp8(u3.y, false);
                const float2v h1 = __builtin_amdgcn_cvt_pk_f32_fp8(u3.y, true);
                a1l.x += l0.x; a1l.y += l0.y; a1l.z += h0.x; a1l.w += h0.y;
                a1h.x += l1.x; a1h.y += l1.y; a1h.z += h1.x; a1h.w += h1.y;
            }
        } else {
#pragma unroll
            for (int k = 0; k < 4; ++k) {
                if (base + k < re) {
                    const int idx = esrc[base + k];
                    const uint2 u = *(const uint2*)(hXW + (size_t)idx * DOS + q * 8);
                    const float2v l0 = __builtin_amdgcn_cvt_pk_f32_fp8(u.x, false);
                    const float2v h0 = __builtin_amdgcn_cvt_pk_f32_fp8(u.x, true);
                    const float2v l1 = __builtin_amdgcn_cvt_pk_f32_fp8(u.y, false);
                    const float2v h1 = __builtin_amdgcn_cvt_pk_f32_fp8(u.y, true);
                    a0l.x += l0.x; a0l.y += l0.y; a0l.z += h0.x; a0l.w += h0.y;
                    a0h.x += l1.x; a0h.y += l1.y; a0h.z += h1.x; a0h.w += h1.y;
                }
            }
        }
    }
    a0l.x += a1l.x; a0l.y += a1l.y; a0l.z += a1l.z; a0l.w += a1l.w;
    a0h.x += a1h.x; a0h.y += a1h.y; a0h.z += a1h.z; a0h.w += a1h.w;
    sred[0][t] = a0l.x; sred[1][t] = a0l.y; sred[2][t] = a0l.z; sred[3][t] = a0l.w;
    sred[4][t] = a0h.x; sred[5][t] = a0h.y; sred[6][t] = a0h.z; sred[7][t] = a0h.w;
    __syncthreads();
    if (t < QN) {
        const int qq = t >> 1, h = t & 1;
        float4 sum = {0.f, 0.f, 0.f, 0.f};
#pragma unroll
        for (int k = 0; k < NG; ++k) {
            const int u = k * CG + qq;
            sum.x += sred[h * 4 + 0][u];
            sum.y += sred[h * 4 + 1][u];
            sum.z += sred[h * 4 + 2][u];
            sum.w += sred[h * 4 + 3][u];
        }
        const float dn = dinv[n];
        // self-loop: stored row n is already dinv[n]*XW[n]
        const unsigned su = *(const unsigned*)(hXW + (size_t)n * DOS + t * 4);
        const float2v slo = __builtin_amdgcn_cvt_pk_f32_fp8(su, false);
        const float2v shi = __builtin_amdgcn_cvt_pk_f32_fp8(su, true);
        const float4 b4 = *(const float4*)(bias + t * 4);
        const float4 g4 = *(const float4*)(g + t * 4);
        const float4 be4 = *(const float4*)(be + t * 4);
        const float4 m4 = *(const float4*)(m + t * 4);
        const float4 v4 = *(const float4*)(v + t * 4);
        float4 val;
        val.x = (sum.x + slo.x) * dn + b4.x;
        val.y = (sum.y + slo.y) * dn + b4.y;
        val.z = (sum.z + shi.x) * dn + b4.z;
        val.w = (sum.w + shi.y) * dn + b4.w;
        val.x = (val.x - m4.x) * (g4.x * rsqrtf(v4.x + EPS)) + be4.x;
        val.y = (val.y - m4.y) * (g4.y * rsqrtf(v4.y + EPS)) + be4.y;
        val.z = (val.z - m4.z) * (g4.z * rsqrtf(v4.z + EPS)) + be4.z;
        val.w = (val.w - m4.w) * (g4.w * rsqrtf(v4.w + EPS)) + be4.w;
        float4* outp = (float4*)(resOut + (size_t)n * DOS + t * 4);
        if (RELU_RES) {
            const float4 r = *outp;
            val.x = fmaxf(val.x, 0.f) + r.x;
            val.y = fmaxf(val.y, 0.f) + r.y;
            val.z = fmaxf(val.z, 0.f) + r.z;
            val.w = fmaxf(val.w, 0.f) + r.w;
            ushort4 bf;
            bf.x = f2bf(val.x); bf.y = f2bf(val.y);
            bf.z = f2bf(val.z); bf.w = f2bf(val.w);
            *(ushort4*)(resBf + (size_t)n * DOS + t * 4) = bf;
        }
        *outp = val;
    }
}

// ---------------- launch ----------------

extern "C" void kernel_launch(void* const* d_in, const int* in_sizes, int n_in,
                              void* d_out, int out_size, void* d_ws, size_t ws_size,
                              hipStream_t stream) {
    const float* x    = (const float*)d_in[0];
    const int*   ei   = (const int*)d_in[1];
    const float* W_in = (const float*)d_in[2];
    const float* b_in = (const float*)d_in[3];
    const float* Wl[3] = {(const float*)d_in[4], (const float*)d_in[10], (const float*)d_in[16]};
    const float* bl[3] = {(const float*)d_in[5], (const float*)d_in[11], (const float*)d_in[17]};
    const float* gl[3] = {(const float*)d_in[6], (const float*)d_in[12], (const float*)d_in[18]};
    const float* bel[3] = {(const float*)d_in[7], (const float*)d_in[13], (const float*)d_in[19]};
    const float* ml[3] = {(const float*)d_in[8], (const float*)d_in[14], (const float*)d_in[20]};
    const float* vl[3] = {(const float*)d_in[9], (const float*)d_in[15], (const float*)d_in[21]};
    float* out = (float*)d_out;

    char* ws = (char*)d_ws;
    size_t off = 0;
    auto carve = [&](size_t bytes) {
        void* p = ws + off;
        off += (bytes + 255) & ~(size_t)255;
        return p;
    };
    int*   bcnt     = (int*)carve(NB * sizeof(int));
    int*   rowstart = (int*)carve((NN + 1) * sizeof(int));
    float* dinv     = (float*)carve(NN * sizeof(float));
    int*   esrc     = (int*)carve((size_t)NE * sizeof(int));
    float* hA       = (float*)carve((size_t)NN * HD * sizeof(float));
    unsigned short* hAbf = (unsigned short*)carve((size_t)NN * HD * sizeof(unsigned short));
    unsigned char* hB = (unsigned char*)carve((size_t)NN * HD);
    int*   ebin     = (int*)carve((size_t)NB * EMAX * sizeof(int));
    unsigned short* wf0 = (unsigned short*)carve((size_t)HD * HD * sizeof(unsigned short));
    unsigned short* wf1 = (unsigned short*)carve((size_t)HD * HD * sizeof(unsigned short));
    unsigned short* wf2 = (unsigned short*)carve((size_t)HD * DD * sizeof(unsigned short));
    (void)ws_size;

    hipMemsetAsync(bcnt, 0, NB * sizeof(int), stream);

    wprep_all<<<80, 64, 0, stream>>>(Wl[0], Wl[1], Wl[2], wf0, wf1, wf2);

    pA_bin<<<NBLK, 256, 0, stream>>>(ei, bcnt, ebin);
    p4_finalize<<<NB, 512, 0, stream>>>(bcnt, ebin, esrc, rowstart, dinv);

    inproj_kernel<<<NN / 2, 256, 0, stream>>>(x, W_in, b_in, hA, hAbf);

    // layer 0
    gemm_mfma<128><<<NN / 32, 256, 0, stream>>>(hAbf, wf0, dinv, hB);
    gather_kernel<128, true><<<NN, 128, 0, stream>>>(hB, hA, hAbf, rowstart, esrc, dinv,
                                                     bl[0], gl[0], bel[0], ml[0], vl[0]);
    // layer 1
    gemm_mfma<128><<<NN / 32, 256, 0, stream>>>(hAbf, wf1, dinv, hB);
    gather_kernel<128, true><<<NN, 128, 0, stream>>>(hB, hA, hAbf, rowstart, esrc, dinv,
                                                     bl[1], gl[1], bel[1], ml[1], vl[1]);
    // layer 2 (BN only, write d_out)
    gemm_mfma<64><<<NN / 32, 256, 0, stream>>>(hAbf, wf2, dinv, hB);
    gather_kernel<64, false><<<NN, 128, 0, stream>>>(hB, out, (unsigned short*)nullptr,
                                                     rowstart, esrc, dinv,
                                                     bl[2], gl[2], bel[2], ml[2], vl[2]);
}

// Round 4
// 504.541 us; speedup vs baseline: 1.4225x; 1.0837x over previous
//
#include <hip/hip_runtime.h>

// NuclideGNN: 3-layer GCN on MI355X.
// R9: hB rows pre-scaled by dinv[src] in GEMM epilogue -> gather is pure
//     row-sum; p1+p3 fused into one LDS-staged pass. Gather: block-per-node,
//     LDS-staged indices, 2-deep row MLP. 83.7us/gather -- best structure.
// R10 (REVERTED): column-split gather -- 128B-line granularity, no win.
// R11 (REVERTED): wave-per-node -- halved MLP, BW 3.36->2.52 TB/s.
// R12 (REVERTED): per-chunk scalar esrc loads put index latency on the row
//     critical path -- BW 2.86 TB/s. LDS staging is the right index path.
// R13: drop the fp32 residual array entirely. Residual chain lives in bf16
//     (hAbf), which the conv path already consumed at bf16. Gather reads
//     residual bf16 (-25.6MB), writes bf16 only (-51.2MB); inproj writes
//     bf16 only (-51.2MB). R9 request structure restored verbatim.
//     Predicted: gather128 FETCH 200->~175MB, WRITE 75->~25MB, dur ->~62-70us.

#define NN 100000
#define NE 3200000
#define FI 7
#define HD 128
#define DD 64
#define EPS 1e-5f
#define NB 196                        // buckets of 512 dst nodes (dst>>9)
#define EPB 8192                      // edges per pA block (256 thr x 32)
#define NBLK ((NE + EPB - 1) / EPB)   // 391
#define EMAX 20000                    // fixed ebin window per bucket (max ~16.7k)

typedef float float2v __attribute__((ext_vector_type(2)));
typedef short short8 __attribute__((ext_vector_type(8)));
typedef float f32x4 __attribute__((ext_vector_type(4)));

__device__ __forceinline__ unsigned char f2fp8(float f) {
    return (unsigned char)(__builtin_amdgcn_cvt_pk_fp8_f32(f, f, 0, false) & 0xFF);
}
__device__ __forceinline__ unsigned short f2bf(float f) {
    unsigned u = __float_as_uint(f);
    u += 0x7FFF + ((u >> 16) & 1);  // RNE
    return (unsigned short)(u >> 16);
}
__device__ __forceinline__ float bf2f(unsigned short s) {
    return __uint_as_float((unsigned)s << 16);
}

// ---------------- CSR build ----------------

__global__ __launch_bounds__(256) void pA_bin(const int* __restrict__ ei,
                                              int* __restrict__ bcnt,
                                              int* __restrict__ ebin) {
    __shared__ int sdst[EPB];   // 32 KB
    __shared__ int hcur[NB];
    const int t = threadIdx.x;
    for (int b = t; b < NB; b += 256) hcur[b] = 0;
    __syncthreads();
    const int base = blockIdx.x * EPB;
    const int cnt = min(EPB, NE - base);
    for (int i = t; i < cnt; i += 256) {
        int d = ei[NE + base + i];
        sdst[i] = d;
        atomicAdd(&hcur[d >> 9], 1);
    }
    __syncthreads();
    for (int b = t; b < NB; b += 256) {
        int c = hcur[b];
        hcur[b] = (c ? atomicAdd(&bcnt[b], c) : 0) + b * EMAX;
    }
    __syncthreads();
    for (int i = t; i < cnt; i += 256) {
        int s = ei[base + i];
        int d = sdst[i];
        int p = atomicAdd(&hcur[d >> 9], 1);
        ebin[p] = ((d & 511) << 23) | s;
    }
}

// p4: local bucket scan (dense esrc offsets) + per-bucket hist/scan/scatter.
__global__ __launch_bounds__(512) void p4_finalize(const int* __restrict__ bcnt,
                                                   const int* __restrict__ ebin,
                                                   int* __restrict__ esrc,
                                                   int* __restrict__ rowstart,
                                                   float* __restrict__ dinv) {
    __shared__ int sh[256];  // bucket-count scan
    __shared__ int lh[512];  // local degree
    __shared__ int sc[512];  // scan buffer
    __shared__ int lc[512];  // local cursor
    const int t = threadIdx.x;
    const int b = blockIdx.x;
    if (t < 256) sh[t] = (t < NB) ? bcnt[t] : 0;
    __syncthreads();
    for (int off = 1; off < 256; off <<= 1) {
        int v = (t < 256 && t >= off) ? sh[t - off] : 0;
        __syncthreads();
        if (t < 256) sh[t] += v;
        __syncthreads();
    }
    const int ecnt = bcnt[b];
    const int ebase = sh[b] - ecnt;   // dense esrc base for this bucket
    const int rbase = b * EMAX;       // padded ebin read base
    const int n0 = b << 9;
    lh[t] = 0;
    __syncthreads();
    for (int i = t; i < ecnt; i += 512)
        atomicAdd(&lh[((unsigned)ebin[rbase + i]) >> 23], 1);
    __syncthreads();
    const int c = lh[t];
    sc[t] = c;
    __syncthreads();
    for (int off = 1; off < 512; off <<= 1) {
        int v = (t >= off) ? sc[t - off] : 0;
        __syncthreads();
        sc[t] += v;
        __syncthreads();
    }
    const int excl = ebase + sc[t] - c;  // global rowstart for node n0+t
    lc[t] = excl;
    const int node = n0 + t;
    if (node < NN) {
        rowstart[node] = excl;
        dinv[node] = rsqrtf((float)c + 1.0f);  // deg includes self-loop
    }
    if (b == NB - 1 && t == 0) rowstart[NN] = NE;
    __syncthreads();
    for (int i = t; i < ecnt; i += 512) {
        int v = ebin[rbase + i];
        int p = atomicAdd(&lc[((unsigned)v) >> 23], 1);
        esrc[p] = v & 0x7FFFFF;  // writes land in a 65KB L2-hot window
    }
}

// --------- input projection: h = relu(x @ W_in + b_in), bf16 only ----------

__global__ __launch_bounds__(256) void inproj_kernel(const float* __restrict__ x,
                                                     const float* __restrict__ W_in,
                                                     const float* __restrict__ b_in,
                                                     unsigned short* __restrict__ hAbf) {
    int n = blockIdx.x * 2 + (threadIdx.x >> 7);
    int j = threadIdx.x & 127;
    float acc = b_in[j];
#pragma unroll
    for (int f = 0; f < FI; ++f) acc += x[n * FI + f] * W_in[f * HD + j];
    acc = fmaxf(acc, 0.f);
    hAbf[n * HD + j] = f2bf(acc);
}

// -------- W pre-swizzle into MFMA B-fragment order (bf16), 3 mats fused -----

__global__ __launch_bounds__(64) void wprep_all(const float* __restrict__ W0,
                                                const float* __restrict__ W1,
                                                const float* __restrict__ W2,
                                                unsigned short* __restrict__ wf0,
                                                unsigned short* __restrict__ wf1,
                                                unsigned short* __restrict__ wf2) {
    const int blk = blockIdx.x;
    const float* W;
    unsigned short* Wf;
    int DO, rel;
    if (blk < 32) { W = W0; Wf = wf0; DO = 128; rel = blk; }
    else if (blk < 64) { W = W1; Wf = wf1; DO = 128; rel = blk - 32; }
    else { W = W2; Wf = wf2; DO = 64; rel = blk - 64; }
    const int lane = threadIdx.x;
    const int nt = rel >> 2;
    const int ks = rel & 3;
    short8 o;
#pragma unroll
    for (int j = 0; j < 8; ++j)
        o[j] = (short)f2bf(W[(ks * 32 + (lane >> 4) * 8 + j) * DO + nt * 16 + (lane & 15)]);
    *(short8*)(Wf + ((size_t)rel * 64 + lane) * 8) = o;
}

// -------- MFMA GEMM: B[N,DO](fp8) = (A[N,128](bf16) @ W) * dinv[row] --------

template <int DO>
__global__ __launch_bounds__(256) void gemm_mfma(const unsigned short* __restrict__ A,
                                                 const unsigned short* __restrict__ Wf,
                                                 const float* __restrict__ dinv,
                                                 unsigned char* __restrict__ B) {
    constexpr int CT = DO / 64;  // col-tiles per wave: 2 (DO=128) or 1 (DO=64)
    const int tid = threadIdx.x;
    const int wave = tid >> 6;
    const int lane = tid & 63;
    const int n0 = blockIdx.x * 32;
    short8 bfrag[CT][4];
#pragma unroll
    for (int ct = 0; ct < CT; ++ct)
#pragma unroll
        for (int ks = 0; ks < 4; ++ks)
            bfrag[ct][ks] = *(const short8*)(Wf + ((size_t)(((wave * CT + ct) * 4 + ks) * 64) + lane) * 8);
#pragma unroll
    for (int rt = 0; rt < 2; ++rt) {
        const int arow = n0 + rt * 16 + (lane & 15);
        short8 afrag[4];
#pragma unroll
        for (int ks = 0; ks < 4; ++ks)
            afrag[ks] = *(const short8*)(A + (size_t)arow * HD + ks * 32 + ((lane >> 4) & 3) * 8);
        f32x4 acc[CT];
#pragma unroll
        for (int ct = 0; ct < CT; ++ct) acc[ct] = (f32x4){0.f, 0.f, 0.f, 0.f};
#pragma unroll
        for (int ks = 0; ks < 4; ++ks)
#pragma unroll
            for (int ct = 0; ct < CT; ++ct)
                acc[ct] = __builtin_amdgcn_mfma_f32_16x16x32_bf16(afrag[ks], bfrag[ct][ks], acc[ct], 0, 0, 0);
#pragma unroll
        for (int r = 0; r < 4; ++r) {
            const int orow = n0 + rt * 16 + (lane >> 4) * 4 + r;
            const float dv = dinv[orow];
#pragma unroll
            for (int ct = 0; ct < CT; ++ct) {
                const int ocol = (wave * CT + ct) * 16 + (lane & 15);
                B[(size_t)orow * DO + ocol] = f2fp8(acc[ct][r] * dv);
            }
        }
    }
}

// ---------- fused gather (pure row-sum) + self-loop + bias + BN (+relu/res) --
// R9 structure verbatim: block (128 thr) per dst node, s_idx LDS staging,
// 2-deep row MLP, sred epilogue. R13: residual chain in bf16 (resBf) only;
// RELU_RES writes bf16 only, !RELU_RES writes fp32 resOut (d_out).

template <int DO, bool RELU_RES>
__global__ __launch_bounds__(128) void gather_kernel(const unsigned char* __restrict__ hXW,
                                                     float* __restrict__ resOut,
                                                     unsigned short* __restrict__ resBf,
                                                     const int* __restrict__ rowstart,
                                                     const int* __restrict__ esrc,
                                                     const float* __restrict__ dinv,
                                                     const float* __restrict__ bias,
                                                     const float* __restrict__ g,
                                                     const float* __restrict__ be,
                                                     const float* __restrict__ m,
                                                     const float* __restrict__ v) {
    constexpr int CG = DO / 8;    // 16 (DO=128) or 8 (DO=64) col-groups
    constexpr int NG = 128 / CG;  // 8 or 16 edge groups
    constexpr int QN = DO / 4;    // output col-quads
    __shared__ int s_idx[128];
    __shared__ float sred[8][128];  // SoA partials
    const int n = blockIdx.x;
    const int t = threadIdx.x;
    const int rs = rowstart[n];
    const int re = rowstart[n + 1];
    const float dn = dinv[n];
    const int q = t & (CG - 1);
    const int grp = t / CG;
    float4 a0l = {0.f, 0.f, 0.f, 0.f}, a0h = {0.f, 0.f, 0.f, 0.f};
    float4 a1l = {0.f, 0.f, 0.f, 0.f}, a1h = {0.f, 0.f, 0.f, 0.f};
    for (int base = rs; base < re; base += 128) {
        const int c = min(128, re - base);
        __syncthreads();
        if (t < c) s_idx[t] = esrc[base + t];
        __syncthreads();
        for (int j = grp; j < c; j += 2 * NG) {
            {
                const uint2 u = *(const uint2*)(hXW + (size_t)s_idx[j] * DO + q * 8);
                const float2v l0 = __builtin_amdgcn_cvt_pk_f32_fp8(u.x, false);
                const float2v h0 = __builtin_amdgcn_cvt_pk_f32_fp8(u.x, true);
                const float2v l1 = __builtin_amdgcn_cvt_pk_f32_fp8(u.y, false);
                const float2v h1 = __builtin_amdgcn_cvt_pk_f32_fp8(u.y, true);
                a0l.x += l0.x; a0l.y += l0.y; a0l.z += h0.x; a0l.w += h0.y;
                a0h.x += l1.x; a0h.y += l1.y; a0h.z += h1.x; a0h.w += h1.y;
            }
            if (j + NG < c) {
                const uint2 u = *(const uint2*)(hXW + (size_t)s_idx[j + NG] * DO + q * 8);
                const float2v l0 = __builtin_amdgcn_cvt_pk_f32_fp8(u.x, false);
                const float2v h0 = __builtin_amdgcn_cvt_pk_f32_fp8(u.x, true);
                const float2v l1 = __builtin_amdgcn_cvt_pk_f32_fp8(u.y, false);
                const float2v h1 = __builtin_amdgcn_cvt_pk_f32_fp8(u.y, true);
                a1l.x += l0.x; a1l.y += l0.y; a1l.z += h0.x; a1l.w += h0.y;
                a1h.x += l1.x; a1h.y += l1.y; a1h.z += h1.x; a1h.w += h1.y;
            }
        }
    }
    a0l.x += a1l.x; a0l.y += a1l.y; a0l.z += a1l.z; a0l.w += a1l.w;
    a0h.x += a1h.x; a0h.y += a1h.y; a0h.z += a1h.z; a0h.w += a1h.w;
    __syncthreads();
    sred[0][t] = a0l.x; sred[1][t] = a0l.y; sred[2][t] = a0l.z; sred[3][t] = a0l.w;
    sred[4][t] = a0h.x; sred[5][t] = a0h.y; sred[6][t] = a0h.z; sred[7][t] = a0h.w;
    __syncthreads();
    if (t < QN) {
        const int qq = t >> 1, h = t & 1;
        float4 sum = {0.f, 0.f, 0.f, 0.f};
#pragma unroll
        for (int k = 0; k < NG; ++k) {
            const int u = k * CG + qq;
            sum.x += sred[h * 4 + 0][u];
            sum.y += sred[h * 4 + 1][u];
            sum.z += sred[h * 4 + 2][u];
            sum.w += sred[h * 4 + 3][u];
        }
        // self-loop: stored row n is already dinv[n]*XW[n]
        const unsigned su = *(const unsigned*)(hXW + (size_t)n * DO + t * 4);
        const float2v slo = __builtin_amdgcn_cvt_pk_f32_fp8(su, false);
        const float2v shi = __builtin_amdgcn_cvt_pk_f32_fp8(su, true);
        const float4 b4 = *(const float4*)(bias + t * 4);
        const float4 g4 = *(const float4*)(g + t * 4);
        const float4 be4 = *(const float4*)(be + t * 4);
        const float4 m4 = *(const float4*)(m + t * 4);
        const float4 v4 = *(const float4*)(v + t * 4);
        float4 val;
        val.x = (sum.x + slo.x) * dn + b4.x;
        val.y = (sum.y + slo.y) * dn + b4.y;
        val.z = (sum.z + shi.x) * dn + b4.z;
        val.w = (sum.w + shi.y) * dn + b4.w;
        val.x = (val.x - m4.x) * (g4.x * rsqrtf(v4.x + EPS)) + be4.x;
        val.y = (val.y - m4.y) * (g4.y * rsqrtf(v4.y + EPS)) + be4.y;
        val.z = (val.z - m4.z) * (g4.z * rsqrtf(v4.z + EPS)) + be4.z;
        val.w = (val.w - m4.w) * (g4.w * rsqrtf(v4.w + EPS)) + be4.w;
        if (RELU_RES) {
            // residual read from the bf16 chain (same values the conv consumed)
            const ushort4 rb = *(const ushort4*)(resBf + (size_t)n * DO + t * 4);
            val.x = fmaxf(val.x, 0.f) + bf2f(rb.x);
            val.y = fmaxf(val.y, 0.f) + bf2f(rb.y);
            val.z = fmaxf(val.z, 0.f) + bf2f(rb.z);
            val.w = fmaxf(val.w, 0.f) + bf2f(rb.w);
            ushort4 bf;
            bf.x = f2bf(val.x); bf.y = f2bf(val.y);
            bf.z = f2bf(val.z); bf.w = f2bf(val.w);
            *(ushort4*)(resBf + (size_t)n * DO + t * 4) = bf;
        } else {
            *(float4*)(resOut + (size_t)n * DO + t * 4) = val;
        }
    }
}

// ---------------- launch ----------------

extern "C" void kernel_launch(void* const* d_in, const int* in_sizes, int n_in,
                              void* d_out, int out_size, void* d_ws, size_t ws_size,
                              hipStream_t stream) {
    const float* x    = (const float*)d_in[0];
    const int*   ei   = (const int*)d_in[1];
    const float* W_in = (const float*)d_in[2];
    const float* b_in = (const float*)d_in[3];
    const float* Wl[3] = {(const float*)d_in[4], (const float*)d_in[10], (const float*)d_in[16]};
    const float* bl[3] = {(const float*)d_in[5], (const float*)d_in[11], (const float*)d_in[17]};
    const float* gl[3] = {(const float*)d_in[6], (const float*)d_in[12], (const float*)d_in[18]};
    const float* bel[3] = {(const float*)d_in[7], (const float*)d_in[13], (const float*)d_in[19]};
    const float* ml[3] = {(const float*)d_in[8], (const float*)d_in[14], (const float*)d_in[20]};
    const float* vl[3] = {(const float*)d_in[9], (const float*)d_in[15], (const float*)d_in[21]};
    float* out = (float*)d_out;

    char* ws = (char*)d_ws;
    size_t off = 0;
    auto carve = [&](size_t bytes) {
        void* p = ws + off;
        off += (bytes + 255) & ~(size_t)255;
        return p;
    };
    int*   bcnt     = (int*)carve(NB * sizeof(int));
    int*   rowstart = (int*)carve((NN + 1) * sizeof(int));
    float* dinv     = (float*)carve(NN * sizeof(float));
    int*   esrc     = (int*)carve((size_t)NE * sizeof(int));
    unsigned short* hAbf = (unsigned short*)carve((size_t)NN * HD * sizeof(unsigned short));
    unsigned char* hB = (unsigned char*)carve((size_t)NN * HD);
    int*   ebin     = (int*)carve((size_t)NB * EMAX * sizeof(int));
    unsigned short* wf0 = (unsigned short*)carve((size_t)HD * HD * sizeof(unsigned short));
    unsigned short* wf1 = (unsigned short*)carve((size_t)HD * HD * sizeof(unsigned short));
    unsigned short* wf2 = (unsigned short*)carve((size_t)HD * DD * sizeof(unsigned short));
    (void)ws_size;

    hipMemsetAsync(bcnt, 0, NB * sizeof(int), stream);

    wprep_all<<<80, 64, 0, stream>>>(Wl[0], Wl[1], Wl[2], wf0, wf1, wf2);

    pA_bin<<<NBLK, 256, 0, stream>>>(ei, bcnt, ebin);
    p4_finalize<<<NB, 512, 0, stream>>>(bcnt, ebin, esrc, rowstart, dinv);

    inproj_kernel<<<NN / 2, 256, 0, stream>>>(x, W_in, b_in, hAbf);

    // layer 0
    gemm_mfma<128><<<NN / 32, 256, 0, stream>>>(hAbf, wf0, dinv, hB);
    gather_kernel<128, true><<<NN, 128, 0, stream>>>(hB, (float*)nullptr, hAbf, rowstart, esrc, dinv,
                                                     bl[0], gl[0], bel[0], ml[0], vl[0]);
    // layer 1
    gemm_mfma<128><<<NN / 32, 256, 0, stream>>>(hAbf, wf1, dinv, hB);
    gather_kernel<128, true><<<NN, 128, 0, stream>>>(hB, (float*)nullptr, hAbf, rowstart, esrc, dinv,
                                                     bl[1], gl[1], bel[1], ml[1], vl[1]);
    // layer 2 (BN only, write d_out)
    gemm_mfma<64><<<NN / 32, 256, 0, stream>>>(hAbf, wf2, dinv, hB);
    gather_kernel<64, false><<<NN, 128, 0, stream>>>(hB, out, (unsigned short*)nullptr,
                                                     rowstart, esrc, dinv,
                                                     bl[2], gl[2], bel[2], ml[2], vl[2]);
}

// Round 5
// 487.081 us; speedup vs baseline: 1.4735x; 1.0358x over previous
//
#include <hip/hip_runtime.h>

// NuclideGNN: 3-layer GCN on MI355X.
// R9:  block-per-node gather, LDS-staged indices, 2-deep row MLP.
// R10 (REVERTED): column-split gather -- 128B-line granularity, no win.
// R11 (REVERTED): wave-per-node -- halved MLP, BW 3.36->2.52 TB/s.
// R12 (REVERTED): scalar esrc loads put index latency on critical path.
// R13: residual chain bf16-only; -70MB/gather. Time ~unchanged => gather is
//     request/instruction-bound, not byte-bound.
// R14: uint4 row loads (16B/lane). CG 16->8 lanes/row: one wave-load covers
//     8 edges (VMEM insts x1/2, vmcnt entries x1/2); cvt+packed-adds cut
//     VALU/byte 1.5->0.75. sred redesigned conflict-free ([16][132] pad,
//     one col/thread). Predicted: gather 82->~60-68us, conflicts 3.2M->~0,
//     FETCH/WRITE unchanged. Null result => line-granule roofline.

#define NN 100000
#define NE 3200000
#define FI 7
#define HD 128
#define DD 64
#define EPS 1e-5f
#define NB 196                        // buckets of 512 dst nodes (dst>>9)
#define EPB 8192                      // edges per pA block (256 thr x 32)
#define NBLK ((NE + EPB - 1) / EPB)   // 391
#define EMAX 20000                    // fixed ebin window per bucket (max ~16.7k)

typedef float float2v __attribute__((ext_vector_type(2)));
typedef short short8 __attribute__((ext_vector_type(8)));
typedef float f32x4 __attribute__((ext_vector_type(4)));
typedef unsigned uintv4 __attribute__((ext_vector_type(4)));

__device__ __forceinline__ unsigned char f2fp8(float f) {
    return (unsigned char)(__builtin_amdgcn_cvt_pk_fp8_f32(f, f, 0, false) & 0xFF);
}
__device__ __forceinline__ unsigned short f2bf(float f) {
    unsigned u = __float_as_uint(f);
    u += 0x7FFF + ((u >> 16) & 1);  // RNE
    return (unsigned short)(u >> 16);
}
__device__ __forceinline__ float bf2f(unsigned short s) {
    return __uint_as_float((unsigned)s << 16);
}

// ---------------- CSR build ----------------

__global__ __launch_bounds__(256) void pA_bin(const int* __restrict__ ei,
                                              int* __restrict__ bcnt,
                                              int* __restrict__ ebin) {
    __shared__ int sdst[EPB];   // 32 KB
    __shared__ int hcur[NB];
    const int t = threadIdx.x;
    for (int b = t; b < NB; b += 256) hcur[b] = 0;
    __syncthreads();
    const int base = blockIdx.x * EPB;
    const int cnt = min(EPB, NE - base);
    for (int i = t; i < cnt; i += 256) {
        int d = ei[NE + base + i];
        sdst[i] = d;
        atomicAdd(&hcur[d >> 9], 1);
    }
    __syncthreads();
    for (int b = t; b < NB; b += 256) {
        int c = hcur[b];
        hcur[b] = (c ? atomicAdd(&bcnt[b], c) : 0) + b * EMAX;
    }
    __syncthreads();
    for (int i = t; i < cnt; i += 256) {
        int s = ei[base + i];
        int d = sdst[i];
        int p = atomicAdd(&hcur[d >> 9], 1);
        ebin[p] = ((d & 511) << 23) | s;
    }
}

// p4: local bucket scan (dense esrc offsets) + per-bucket hist/scan/scatter.
__global__ __launch_bounds__(512) void p4_finalize(const int* __restrict__ bcnt,
                                                   const int* __restrict__ ebin,
                                                   int* __restrict__ esrc,
                                                   int* __restrict__ rowstart,
                                                   float* __restrict__ dinv) {
    __shared__ int sh[256];  // bucket-count scan
    __shared__ int lh[512];  // local degree
    __shared__ int sc[512];  // scan buffer
    __shared__ int lc[512];  // local cursor
    const int t = threadIdx.x;
    const int b = blockIdx.x;
    if (t < 256) sh[t] = (t < NB) ? bcnt[t] : 0;
    __syncthreads();
    for (int off = 1; off < 256; off <<= 1) {
        int v = (t < 256 && t >= off) ? sh[t - off] : 0;
        __syncthreads();
        if (t < 256) sh[t] += v;
        __syncthreads();
    }
    const int ecnt = bcnt[b];
    const int ebase = sh[b] - ecnt;   // dense esrc base for this bucket
    const int rbase = b * EMAX;       // padded ebin read base
    const int n0 = b << 9;
    lh[t] = 0;
    __syncthreads();
    for (int i = t; i < ecnt; i += 512)
        atomicAdd(&lh[((unsigned)ebin[rbase + i]) >> 23], 1);
    __syncthreads();
    const int c = lh[t];
    sc[t] = c;
    __syncthreads();
    for (int off = 1; off < 512; off <<= 1) {
        int v = (t >= off) ? sc[t - off] : 0;
        __syncthreads();
        sc[t] += v;
        __syncthreads();
    }
    const int excl = ebase + sc[t] - c;  // global rowstart for node n0+t
    lc[t] = excl;
    const int node = n0 + t;
    if (node < NN) {
        rowstart[node] = excl;
        dinv[node] = rsqrtf((float)c + 1.0f);  // deg includes self-loop
    }
    if (b == NB - 1 && t == 0) rowstart[NN] = NE;
    __syncthreads();
    for (int i = t; i < ecnt; i += 512) {
        int v = ebin[rbase + i];
        int p = atomicAdd(&lc[((unsigned)v) >> 23], 1);
        esrc[p] = v & 0x7FFFFF;  // writes land in a 65KB L2-hot window
    }
}

// --------- input projection: h = relu(x @ W_in + b_in), bf16 only ----------

__global__ __launch_bounds__(256) void inproj_kernel(const float* __restrict__ x,
                                                     const float* __restrict__ W_in,
                                                     const float* __restrict__ b_in,
                                                     unsigned short* __restrict__ hAbf) {
    int n = blockIdx.x * 2 + (threadIdx.x >> 7);
    int j = threadIdx.x & 127;
    float acc = b_in[j];
#pragma unroll
    for (int f = 0; f < FI; ++f) acc += x[n * FI + f] * W_in[f * HD + j];
    acc = fmaxf(acc, 0.f);
    hAbf[n * HD + j] = f2bf(acc);
}

// -------- W pre-swizzle into MFMA B-fragment order (bf16), 3 mats fused -----

__global__ __launch_bounds__(64) void wprep_all(const float* __restrict__ W0,
                                                const float* __restrict__ W1,
                                                const float* __restrict__ W2,
                                                unsigned short* __restrict__ wf0,
                                                unsigned short* __restrict__ wf1,
                                                unsigned short* __restrict__ wf2) {
    const int blk = blockIdx.x;
    const float* W;
    unsigned short* Wf;
    int DO, rel;
    if (blk < 32) { W = W0; Wf = wf0; DO = 128; rel = blk; }
    else if (blk < 64) { W = W1; Wf = wf1; DO = 128; rel = blk - 32; }
    else { W = W2; Wf = wf2; DO = 64; rel = blk - 64; }
    const int lane = threadIdx.x;
    const int nt = rel >> 2;
    const int ks = rel & 3;
    short8 o;
#pragma unroll
    for (int j = 0; j < 8; ++j)
        o[j] = (short)f2bf(W[(ks * 32 + (lane >> 4) * 8 + j) * DO + nt * 16 + (lane & 15)]);
    *(short8*)(Wf + ((size_t)rel * 64 + lane) * 8) = o;
}

// -------- MFMA GEMM: B[N,DO](fp8) = (A[N,128](bf16) @ W) * dinv[row] --------

template <int DO>
__global__ __launch_bounds__(256) void gemm_mfma(const unsigned short* __restrict__ A,
                                                 const unsigned short* __restrict__ Wf,
                                                 const float* __restrict__ dinv,
                                                 unsigned char* __restrict__ B) {
    constexpr int CT = DO / 64;  // col-tiles per wave: 2 (DO=128) or 1 (DO=64)
    const int tid = threadIdx.x;
    const int wave = tid >> 6;
    const int lane = tid & 63;
    const int n0 = blockIdx.x * 32;
    short8 bfrag[CT][4];
#pragma unroll
    for (int ct = 0; ct < CT; ++ct)
#pragma unroll
        for (int ks = 0; ks < 4; ++ks)
            bfrag[ct][ks] = *(const short8*)(Wf + ((size_t)(((wave * CT + ct) * 4 + ks) * 64) + lane) * 8);
#pragma unroll
    for (int rt = 0; rt < 2; ++rt) {
        const int arow = n0 + rt * 16 + (lane & 15);
        short8 afrag[4];
#pragma unroll
        for (int ks = 0; ks < 4; ++ks)
            afrag[ks] = *(const short8*)(A + (size_t)arow * HD + ks * 32 + ((lane >> 4) & 3) * 8);
        f32x4 acc[CT];
#pragma unroll
        for (int ct = 0; ct < CT; ++ct) acc[ct] = (f32x4){0.f, 0.f, 0.f, 0.f};
#pragma unroll
        for (int ks = 0; ks < 4; ++ks)
#pragma unroll
            for (int ct = 0; ct < CT; ++ct)
                acc[ct] = __builtin_amdgcn_mfma_f32_16x16x32_bf16(afrag[ks], bfrag[ct][ks], acc[ct], 0, 0, 0);
#pragma unroll
        for (int r = 0; r < 4; ++r) {
            const int orow = n0 + rt * 16 + (lane >> 4) * 4 + r;
            const float dv = dinv[orow];
#pragma unroll
            for (int ct = 0; ct < CT; ++ct) {
                const int ocol = (wave * CT + ct) * 16 + (lane & 15);
                B[(size_t)orow * DO + ocol] = f2fp8(acc[ct][r] * dv);
            }
        }
    }
}

// ---------- fused gather (pure row-sum) + self-loop + bias + BN (+relu/res) --
// R14: block (128 thr) per dst node, s_idx LDS staging, 2-deep row MLP,
// uint4 (16B/lane) row loads: CG=DO/16 lanes per row, NG=128/CG edge groups.
// sred [16][132] (pad -> conflict-free), one output column per thread.

template <int DO, bool RELU_RES>
__global__ __launch_bounds__(128) void gather_kernel(const unsigned char* __restrict__ hXW,
                                                     float* __restrict__ resOut,
                                                     unsigned short* __restrict__ resBf,
                                                     const int* __restrict__ rowstart,
                                                     const int* __restrict__ esrc,
                                                     const float* __restrict__ dinv,
                                                     const float* __restrict__ bias,
                                                     const float* __restrict__ g,
                                                     const float* __restrict__ be,
                                                     const float* __restrict__ m,
                                                     const float* __restrict__ v) {
    constexpr int CG = DO / 16;   // lanes per row: 8 (DO=128) or 4 (DO=64)
    constexpr int NG = 128 / CG;  // edge groups: 16 or 32
    __shared__ int s_idx[128];
    __shared__ float sred[16][132];  // padded: write t-major, read k*CG+q
    const int n = blockIdx.x;
    const int t = threadIdx.x;
    const int rs = rowstart[n];
    const int re = rowstart[n + 1];
    const float dn = dinv[n];
    const int q = t & (CG - 1);
    const int grp = t / CG;
    float2v aL[4], aH[4], bL[4], bH[4];
#pragma unroll
    for (int w = 0; w < 4; ++w) {
        aL[w] = (float2v){0.f, 0.f}; aH[w] = (float2v){0.f, 0.f};
        bL[w] = (float2v){0.f, 0.f}; bH[w] = (float2v){0.f, 0.f};
    }
    for (int base = rs; base < re; base += 128) {
        const int c = min(128, re - base);
        __syncthreads();
        if (t < c) s_idx[t] = esrc[base + t];
        __syncthreads();
        for (int j = grp; j < c; j += 2 * NG) {
            {
                const uintv4 u = *(const uintv4*)(hXW + (size_t)s_idx[j] * DO + q * 16);
#pragma unroll
                for (int w = 0; w < 4; ++w) {
                    aL[w] += __builtin_amdgcn_cvt_pk_f32_fp8(u[w], false);
                    aH[w] += __builtin_amdgcn_cvt_pk_f32_fp8(u[w], true);
                }
            }
            if (j + NG < c) {
                const uintv4 u = *(const uintv4*)(hXW + (size_t)s_idx[j + NG] * DO + q * 16);
#pragma unroll
                for (int w = 0; w < 4; ++w) {
                    bL[w] += __builtin_amdgcn_cvt_pk_f32_fp8(u[w], false);
                    bH[w] += __builtin_amdgcn_cvt_pk_f32_fp8(u[w], true);
                }
            }
        }
    }
#pragma unroll
    for (int w = 0; w < 4; ++w) { aL[w] += bL[w]; aH[w] += bH[w]; }
#pragma unroll
    for (int w = 0; w < 4; ++w) {
        sred[4 * w + 0][t] = aL[w].x;
        sred[4 * w + 1][t] = aL[w].y;
        sred[4 * w + 2][t] = aH[w].x;
        sred[4 * w + 3][t] = aH[w].y;
    }
    __syncthreads();
    if (t < DO) {
        // col t: held by lanes with q2 = t>>4 at slot s = t&15
        const int s = t & 15;
        const int q2 = t >> 4;
        float sum = 0.f;
#pragma unroll
        for (int k = 0; k < NG; ++k) sum += sred[s][k * CG + q2];
        // self-loop: stored row n is already dinv[n]*XW[n]
        const unsigned su = *(const unsigned*)(hXW + (size_t)n * DO + (t & ~3));
        const float2v pLo = __builtin_amdgcn_cvt_pk_f32_fp8(su, false);
        const float2v pHi = __builtin_amdgcn_cvt_pk_f32_fp8(su, true);
        const float slf = (t & 2) ? ((t & 1) ? pHi.y : pHi.x)
                                  : ((t & 1) ? pLo.y : pLo.x);
        float val = (sum + slf) * dn + bias[t];
        val = (val - m[t]) * (g[t] * rsqrtf(v[t] + EPS)) + be[t];
        if (RELU_RES) {
            val = fmaxf(val, 0.f) + bf2f(resBf[(size_t)n * DO + t]);
            resBf[(size_t)n * DO + t] = f2bf(val);
        } else {
            resOut[(size_t)n * DO + t] = val;
        }
    }
}

// ---------------- launch ----------------

extern "C" void kernel_launch(void* const* d_in, const int* in_sizes, int n_in,
                              void* d_out, int out_size, void* d_ws, size_t ws_size,
                              hipStream_t stream) {
    const float* x    = (const float*)d_in[0];
    const int*   ei   = (const int*)d_in[1];
    const float* W_in = (const float*)d_in[2];
    const float* b_in = (const float*)d_in[3];
    const float* Wl[3] = {(const float*)d_in[4], (const float*)d_in[10], (const float*)d_in[16]};
    const float* bl[3] = {(const float*)d_in[5], (const float*)d_in[11], (const float*)d_in[17]};
    const float* gl[3] = {(const float*)d_in[6], (const float*)d_in[12], (const float*)d_in[18]};
    const float* bel[3] = {(const float*)d_in[7], (const float*)d_in[13], (const float*)d_in[19]};
    const float* ml[3] = {(const float*)d_in[8], (const float*)d_in[14], (const float*)d_in[20]};
    const float* vl[3] = {(const float*)d_in[9], (const float*)d_in[15], (const float*)d_in[21]};
    float* out = (float*)d_out;

    char* ws = (char*)d_ws;
    size_t off = 0;
    auto carve = [&](size_t bytes) {
        void* p = ws + off;
        off += (bytes + 255) & ~(size_t)255;
        return p;
    };
    int*   bcnt     = (int*)carve(NB * sizeof(int));
    int*   rowstart = (int*)carve((NN + 1) * sizeof(int));
    float* dinv     = (float*)carve(NN * sizeof(float));
    int*   esrc     = (int*)carve((size_t)NE * sizeof(int));
    unsigned short* hAbf = (unsigned short*)carve((size_t)NN * HD * sizeof(unsigned short));
    unsigned char* hB = (unsigned char*)carve((size_t)NN * HD);
    int*   ebin     = (int*)carve((size_t)NB * EMAX * sizeof(int));
    unsigned short* wf0 = (unsigned short*)carve((size_t)HD * HD * sizeof(unsigned short));
    unsigned short* wf1 = (unsigned short*)carve((size_t)HD * HD * sizeof(unsigned short));
    unsigned short* wf2 = (unsigned short*)carve((size_t)HD * DD * sizeof(unsigned short));
    (void)ws_size;

    hipMemsetAsync(bcnt, 0, NB * sizeof(int), stream);

    wprep_all<<<80, 64, 0, stream>>>(Wl[0], Wl[1], Wl[2], wf0, wf1, wf2);

    pA_bin<<<NBLK, 256, 0, stream>>>(ei, bcnt, ebin);
    p4_finalize<<<NB, 512, 0, stream>>>(bcnt, ebin, esrc, rowstart, dinv);

    inproj_kernel<<<NN / 2, 256, 0, stream>>>(x, W_in, b_in, hAbf);

    // layer 0
    gemm_mfma<128><<<NN / 32, 256, 0, stream>>>(hAbf, wf0, dinv, hB);
    gather_kernel<128, true><<<NN, 128, 0, stream>>>(hB, (float*)nullptr, hAbf, rowstart, esrc, dinv,
                                                     bl[0], gl[0], bel[0], ml[0], vl[0]);
    // layer 1
    gemm_mfma<128><<<NN / 32, 256, 0, stream>>>(hAbf, wf1, dinv, hB);
    gather_kernel<128, true><<<NN, 128, 0, stream>>>(hB, (float*)nullptr, hAbf, rowstart, esrc, dinv,
                                                     bl[1], gl[1], bel[1], ml[1], vl[1]);
    // layer 2 (BN only, write d_out)
    gemm_mfma<64><<<NN / 32, 256, 0, stream>>>(hAbf, wf2, dinv, hB);
    gather_kernel<64, false><<<NN, 128, 0, stream>>>(hB, out, (unsigned short*)nullptr,
                                                     rowstart, esrc, dinv,
                                                     bl[2], gl[2], bel[2], ml[2], vl[2]);
}

// Round 6
// 473.642 us; speedup vs baseline: 1.5153x; 1.0284x over previous
//
#include <hip/hip_runtime.h>

// NuclideGNN: 3-layer GCN on MI355X.
// R9:  block-per-node gather, LDS-staged indices, 2-deep row MLP.
// R10 (REVERTED): column-split gather -- 128B-line granularity, no win.
// R11 (REVERTED): wave-per-node -- halved MLP, BW 3.36->2.52 TB/s.
// R12 (REVERTED): scalar esrc loads put index latency on critical path.
// R13: residual chain bf16-only; -70MB/gather => gather not byte-bound.
// R14: uint4 row loads (16B/lane), VMEM insts x1/2 => only -5%. Arithmetic:
//     1.4M L2-miss lines / 8 XCD / 2.4GHz = 74us ~= measured 78us. Gather is
//     L2-miss-service-rate bound; ~at floor (table 12.8MB > 4MB L2/XCD).
// R15: pA_bin scatter de-thrash. Old: 3.2M random 4B writes, each frontier
//     line dirtied by all 8 XCDs (non-coherent L2 ping-pong via L3 + RFO).
//     New: block-local LDS counting-sort (hist -> scan -> reorder in LDS)
//     then contiguous per-bucket run copies to the reserved windows --
//     coalesced, one XCD per run. Predict total 487 -> ~455-470us; if <8us
//     delta, pA wasn't the hidden cost -> pivot to p4 / fusion.

#define NN 100000
#define NE 3200000
#define FI 7
#define HD 128
#define DD 64
#define EPS 1e-5f
#define NB 196                        // buckets of 512 dst nodes (dst>>9)
#define EPB 8192                      // edges per pA block (256 thr x 32)
#define NBLK ((NE + EPB - 1) / EPB)   // 391
#define EMAX 20000                    // fixed ebin window per bucket (max ~16.7k)

typedef float float2v __attribute__((ext_vector_type(2)));
typedef short short8 __attribute__((ext_vector_type(8)));
typedef float f32x4 __attribute__((ext_vector_type(4)));
typedef unsigned uintv4 __attribute__((ext_vector_type(4)));

__device__ __forceinline__ unsigned char f2fp8(float f) {
    return (unsigned char)(__builtin_amdgcn_cvt_pk_fp8_f32(f, f, 0, false) & 0xFF);
}
__device__ __forceinline__ unsigned short f2bf(float f) {
    unsigned u = __float_as_uint(f);
    u += 0x7FFF + ((u >> 16) & 1);  // RNE
    return (unsigned short)(u >> 16);
}
__device__ __forceinline__ float bf2f(unsigned short s) {
    return __uint_as_float((unsigned)s << 16);
}

// ---------------- CSR build ----------------
// pA (R15): per-block LDS counting-sort by bucket, then contiguous window
// writes. Removes cross-XCD 4B-scatter line ping-pong.

__global__ __launch_bounds__(256) void pA_bin(const int* __restrict__ ei,
                                              int* __restrict__ bcnt,
                                              int* __restrict__ ebin) {
    __shared__ int rec[EPB];            // 32 KB reordered records
    __shared__ unsigned char bk[EPB];   // 8 KB bucket id per slot
    __shared__ int ls[256];             // scan buffer -> exclusive starts
    __shared__ int cur[NB];             // local cursors
    __shared__ int gb[NB];              // global window base per bucket
    const int t = threadIdx.x;
    const int base = blockIdx.x * EPB;
    const int cnt = min(EPB, NE - base);
    __shared__ int hc[256];
    hc[t] = 0;
    __syncthreads();
    for (int i = t; i < cnt; i += 256)
        atomicAdd(&hc[ei[NE + base + i] >> 9], 1);
    __syncthreads();
    const int myc = hc[t];
    if (t < NB) gb[t] = (myc ? atomicAdd(&bcnt[t], myc) : 0) + t * EMAX;
    ls[t] = myc;
    __syncthreads();
    for (int off = 1; off < 256; off <<= 1) {
        int v = (t >= off) ? ls[t - off] : 0;
        __syncthreads();
        ls[t] += v;
        __syncthreads();
    }
    const int excl = ls[t] - myc;
    __syncthreads();
    ls[t] = excl;
    if (t < NB) cur[t] = excl;
    __syncthreads();
    // reorder records into LDS, sorted by bucket
    for (int i = t; i < cnt; i += 256) {
        int s = ei[base + i];
        int d = ei[NE + base + i];
        int b = d >> 9;
        int p = atomicAdd(&cur[b], 1);
        rec[p] = ((d & 511) << 23) | s;
        bk[p] = (unsigned char)b;
    }
    __syncthreads();
    // contiguous, single-XCD writes into each bucket's reserved run
    for (int i = t; i < cnt; i += 256) {
        int b = bk[i];
        ebin[gb[b] + (i - ls[b])] = rec[i];
    }
}

// p4: local bucket scan (dense esrc offsets) + per-bucket hist/scan/scatter.
__global__ __launch_bounds__(512) void p4_finalize(const int* __restrict__ bcnt,
                                                   const int* __restrict__ ebin,
                                                   int* __restrict__ esrc,
                                                   int* __restrict__ rowstart,
                                                   float* __restrict__ dinv) {
    __shared__ int sh[256];  // bucket-count scan
    __shared__ int lh[512];  // local degree
    __shared__ int sc[512];  // scan buffer
    __shared__ int lc[512];  // local cursor
    const int t = threadIdx.x;
    const int b = blockIdx.x;
    if (t < 256) sh[t] = (t < NB) ? bcnt[t] : 0;
    __syncthreads();
    for (int off = 1; off < 256; off <<= 1) {
        int v = (t < 256 && t >= off) ? sh[t - off] : 0;
        __syncthreads();
        if (t < 256) sh[t] += v;
        __syncthreads();
    }
    const int ecnt = bcnt[b];
    const int ebase = sh[b] - ecnt;   // dense esrc base for this bucket
    const int rbase = b * EMAX;       // padded ebin read base
    const int n0 = b << 9;
    lh[t] = 0;
    __syncthreads();
    for (int i = t; i < ecnt; i += 512)
        atomicAdd(&lh[((unsigned)ebin[rbase + i]) >> 23], 1);
    __syncthreads();
    const int c = lh[t];
    sc[t] = c;
    __syncthreads();
    for (int off = 1; off < 512; off <<= 1) {
        int v = (t >= off) ? sc[t - off] : 0;
        __syncthreads();
        sc[t] += v;
        __syncthreads();
    }
    const int excl = ebase + sc[t] - c;  // global rowstart for node n0+t
    lc[t] = excl;
    const int node = n0 + t;
    if (node < NN) {
        rowstart[node] = excl;
        dinv[node] = rsqrtf((float)c + 1.0f);  // deg includes self-loop
    }
    if (b == NB - 1 && t == 0) rowstart[NN] = NE;
    __syncthreads();
    for (int i = t; i < ecnt; i += 512) {
        int v = ebin[rbase + i];
        int p = atomicAdd(&lc[((unsigned)v) >> 23], 1);
        esrc[p] = v & 0x7FFFFF;  // writes land in a 65KB L2-hot window
    }
}

// --------- input projection: h = relu(x @ W_in + b_in), bf16 only ----------

__global__ __launch_bounds__(256) void inproj_kernel(const float* __restrict__ x,
                                                     const float* __restrict__ W_in,
                                                     const float* __restrict__ b_in,
                                                     unsigned short* __restrict__ hAbf) {
    int n = blockIdx.x * 2 + (threadIdx.x >> 7);
    int j = threadIdx.x & 127;
    float acc = b_in[j];
#pragma unroll
    for (int f = 0; f < FI; ++f) acc += x[n * FI + f] * W_in[f * HD + j];
    acc = fmaxf(acc, 0.f);
    hAbf[n * HD + j] = f2bf(acc);
}

// -------- W pre-swizzle into MFMA B-fragment order (bf16), 3 mats fused -----

__global__ __launch_bounds__(64) void wprep_all(const float* __restrict__ W0,
                                                const float* __restrict__ W1,
                                                const float* __restrict__ W2,
                                                unsigned short* __restrict__ wf0,
                                                unsigned short* __restrict__ wf1,
                                                unsigned short* __restrict__ wf2) {
    const int blk = blockIdx.x;
    const float* W;
    unsigned short* Wf;
    int DO, rel;
    if (blk < 32) { W = W0; Wf = wf0; DO = 128; rel = blk; }
    else if (blk < 64) { W = W1; Wf = wf1; DO = 128; rel = blk - 32; }
    else { W = W2; Wf = wf2; DO = 64; rel = blk - 64; }
    const int lane = threadIdx.x;
    const int nt = rel >> 2;
    const int ks = rel & 3;
    short8 o;
#pragma unroll
    for (int j = 0; j < 8; ++j)
        o[j] = (short)f2bf(W[(ks * 32 + (lane >> 4) * 8 + j) * DO + nt * 16 + (lane & 15)]);
    *(short8*)(Wf + ((size_t)rel * 64 + lane) * 8) = o;
}

// -------- MFMA GEMM: B[N,DO](fp8) = (A[N,128](bf16) @ W) * dinv[row] --------

template <int DO>
__global__ __launch_bounds__(256) void gemm_mfma(const unsigned short* __restrict__ A,
                                                 const unsigned short* __restrict__ Wf,
                                                 const float* __restrict__ dinv,
                                                 unsigned char* __restrict__ B) {
    constexpr int CT = DO / 64;  // col-tiles per wave: 2 (DO=128) or 1 (DO=64)
    const int tid = threadIdx.x;
    const int wave = tid >> 6;
    const int lane = tid & 63;
    const int n0 = blockIdx.x * 32;
    short8 bfrag[CT][4];
#pragma unroll
    for (int ct = 0; ct < CT; ++ct)
#pragma unroll
        for (int ks = 0; ks < 4; ++ks)
            bfrag[ct][ks] = *(const short8*)(Wf + ((size_t)(((wave * CT + ct) * 4 + ks) * 64) + lane) * 8);
#pragma unroll
    for (int rt = 0; rt < 2; ++rt) {
        const int arow = n0 + rt * 16 + (lane & 15);
        short8 afrag[4];
#pragma unroll
        for (int ks = 0; ks < 4; ++ks)
            afrag[ks] = *(const short8*)(A + (size_t)arow * HD + ks * 32 + ((lane >> 4) & 3) * 8);
        f32x4 acc[CT];
#pragma unroll
        for (int ct = 0; ct < CT; ++ct) acc[ct] = (f32x4){0.f, 0.f, 0.f, 0.f};
#pragma unroll
        for (int ks = 0; ks < 4; ++ks)
#pragma unroll
            for (int ct = 0; ct < CT; ++ct)
                acc[ct] = __builtin_amdgcn_mfma_f32_16x16x32_bf16(afrag[ks], bfrag[ct][ks], acc[ct], 0, 0, 0);
#pragma unroll
        for (int r = 0; r < 4; ++r) {
            const int orow = n0 + rt * 16 + (lane >> 4) * 4 + r;
            const float dv = dinv[orow];
#pragma unroll
            for (int ct = 0; ct < CT; ++ct) {
                const int ocol = (wave * CT + ct) * 16 + (lane & 15);
                B[(size_t)orow * DO + ocol] = f2fp8(acc[ct][r] * dv);
            }
        }
    }
}

// ---------- fused gather (pure row-sum) + self-loop + bias + BN (+relu/res) --
// R14: block (128 thr) per dst node, s_idx LDS staging, 2-deep row MLP,
// uint4 (16B/lane) row loads: CG=DO/16 lanes per row, NG=128/CG edge groups.
// sred [16][132] (pad -> conflict-free), one output column per thread.

template <int DO, bool RELU_RES>
__global__ __launch_bounds__(128) void gather_kernel(const unsigned char* __restrict__ hXW,
                                                     float* __restrict__ resOut,
                                                     unsigned short* __restrict__ resBf,
                                                     const int* __restrict__ rowstart,
                                                     const int* __restrict__ esrc,
                                                     const float* __restrict__ dinv,
                                                     const float* __restrict__ bias,
                                                     const float* __restrict__ g,
                                                     const float* __restrict__ be,
                                                     const float* __restrict__ m,
                                                     const float* __restrict__ v) {
    constexpr int CG = DO / 16;   // lanes per row: 8 (DO=128) or 4 (DO=64)
    constexpr int NG = 128 / CG;  // edge groups: 16 or 32
    __shared__ int s_idx[128];
    __shared__ float sred[16][132];  // padded: write t-major, read k*CG+q
    const int n = blockIdx.x;
    const int t = threadIdx.x;
    const int rs = rowstart[n];
    const int re = rowstart[n + 1];
    const float dn = dinv[n];
    const int q = t & (CG - 1);
    const int grp = t / CG;
    float2v aL[4], aH[4], bL[4], bH[4];
#pragma unroll
    for (int w = 0; w < 4; ++w) {
        aL[w] = (float2v){0.f, 0.f}; aH[w] = (float2v){0.f, 0.f};
        bL[w] = (float2v){0.f, 0.f}; bH[w] = (float2v){0.f, 0.f};
    }
    for (int base = rs; base < re; base += 128) {
        const int c = min(128, re - base);
        __syncthreads();
        if (t < c) s_idx[t] = esrc[base + t];
        __syncthreads();
        for (int j = grp; j < c; j += 2 * NG) {
            {
                const uintv4 u = *(const uintv4*)(hXW + (size_t)s_idx[j] * DO + q * 16);
#pragma unroll
                for (int w = 0; w < 4; ++w) {
                    aL[w] += __builtin_amdgcn_cvt_pk_f32_fp8(u[w], false);
                    aH[w] += __builtin_amdgcn_cvt_pk_f32_fp8(u[w], true);
                }
            }
            if (j + NG < c) {
                const uintv4 u = *(const uintv4*)(hXW + (size_t)s_idx[j + NG] * DO + q * 16);
#pragma unroll
                for (int w = 0; w < 4; ++w) {
                    bL[w] += __builtin_amdgcn_cvt_pk_f32_fp8(u[w], false);
                    bH[w] += __builtin_amdgcn_cvt_pk_f32_fp8(u[w], true);
                }
            }
        }
    }
#pragma unroll
    for (int w = 0; w < 4; ++w) { aL[w] += bL[w]; aH[w] += bH[w]; }
#pragma unroll
    for (int w = 0; w < 4; ++w) {
        sred[4 * w + 0][t] = aL[w].x;
        sred[4 * w + 1][t] = aL[w].y;
        sred[4 * w + 2][t] = aH[w].x;
        sred[4 * w + 3][t] = aH[w].y;
    }
    __syncthreads();
    if (t < DO) {
        // col t: held by lanes with q2 = t>>4 at slot s = t&15
        const int s = t & 15;
        const int q2 = t >> 4;
        float sum = 0.f;
#pragma unroll
        for (int k = 0; k < NG; ++k) sum += sred[s][k * CG + q2];
        // self-loop: stored row n is already dinv[n]*XW[n]
        const unsigned su = *(const unsigned*)(hXW + (size_t)n * DO + (t & ~3));
        const float2v pLo = __builtin_amdgcn_cvt_pk_f32_fp8(su, false);
        const float2v pHi = __builtin_amdgcn_cvt_pk_f32_fp8(su, true);
        const float slf = (t & 2) ? ((t & 1) ? pHi.y : pHi.x)
                                  : ((t & 1) ? pLo.y : pLo.x);
        float val = (sum + slf) * dn + bias[t];
        val = (val - m[t]) * (g[t] * rsqrtf(v[t] + EPS)) + be[t];
        if (RELU_RES) {
            val = fmaxf(val, 0.f) + bf2f(resBf[(size_t)n * DO + t]);
            resBf[(size_t)n * DO + t] = f2bf(val);
        } else {
            resOut[(size_t)n * DO + t] = val;
        }
    }
}

// ---------------- launch ----------------

extern "C" void kernel_launch(void* const* d_in, const int* in_sizes, int n_in,
                              void* d_out, int out_size, void* d_ws, size_t ws_size,
                              hipStream_t stream) {
    const float* x    = (const float*)d_in[0];
    const int*   ei   = (const int*)d_in[1];
    const float* W_in = (const float*)d_in[2];
    const float* b_in = (const float*)d_in[3];
    const float* Wl[3] = {(const float*)d_in[4], (const float*)d_in[10], (const float*)d_in[16]};
    const float* bl[3] = {(const float*)d_in[5], (const float*)d_in[11], (const float*)d_in[17]};
    const float* gl[3] = {(const float*)d_in[6], (const float*)d_in[12], (const float*)d_in[18]};
    const float* bel[3] = {(const float*)d_in[7], (const float*)d_in[13], (const float*)d_in[19]};
    const float* ml[3] = {(const float*)d_in[8], (const float*)d_in[14], (const float*)d_in[20]};
    const float* vl[3] = {(const float*)d_in[9], (const float*)d_in[15], (const float*)d_in[21]};
    float* out = (float*)d_out;

    char* ws = (char*)d_ws;
    size_t off = 0;
    auto carve = [&](size_t bytes) {
        void* p = ws + off;
        off += (bytes + 255) & ~(size_t)255;
        return p;
    };
    int*   bcnt     = (int*)carve(NB * sizeof(int));
    int*   rowstart = (int*)carve((NN + 1) * sizeof(int));
    float* dinv     = (float*)carve(NN * sizeof(float));
    int*   esrc     = (int*)carve((size_t)NE * sizeof(int));
    unsigned short* hAbf = (unsigned short*)carve((size_t)NN * HD * sizeof(unsigned short));
    unsigned char* hB = (unsigned char*)carve((size_t)NN * HD);
    int*   ebin     = (int*)carve((size_t)NB * EMAX * sizeof(int));
    unsigned short* wf0 = (unsigned short*)carve((size_t)HD * HD * sizeof(unsigned short));
    unsigned short* wf1 = (unsigned short*)carve((size_t)HD * HD * sizeof(unsigned short));
    unsigned short* wf2 = (unsigned short*)carve((size_t)HD * DD * sizeof(unsigned short));
    (void)ws_size;

    hipMemsetAsync(bcnt, 0, NB * sizeof(int), stream);

    wprep_all<<<80, 64, 0, stream>>>(Wl[0], Wl[1], Wl[2], wf0, wf1, wf2);

    pA_bin<<<NBLK, 256, 0, stream>>>(ei, bcnt, ebin);
    p4_finalize<<<NB, 512, 0, stream>>>(bcnt, ebin, esrc, rowstart, dinv);

    inproj_kernel<<<NN / 2, 256, 0, stream>>>(x, W_in, b_in, hAbf);

    // layer 0
    gemm_mfma<128><<<NN / 32, 256, 0, stream>>>(hAbf, wf0, dinv, hB);
    gather_kernel<128, true><<<NN, 128, 0, stream>>>(hB, (float*)nullptr, hAbf, rowstart, esrc, dinv,
                                                     bl[0], gl[0], bel[0], ml[0], vl[0]);
    // layer 1
    gemm_mfma<128><<<NN / 32, 256, 0, stream>>>(hAbf, wf1, dinv, hB);
    gather_kernel<128, true><<<NN, 128, 0, stream>>>(hB, (float*)nullptr, hAbf, rowstart, esrc, dinv,
                                                     bl[1], gl[1], bel[1], ml[1], vl[1]);
    // layer 2 (BN only, write d_out)
    gemm_mfma<64><<<NN / 32, 256, 0, stream>>>(hAbf, wf2, dinv, hB);
    gather_kernel<64, false><<<NN, 128, 0, stream>>>(hB, out, (unsigned short*)nullptr,
                                                     rowstart, esrc, dinv,
                                                     bl[2], gl[2], bel[2], ml[2], vl[2]);
}

// Round 7
// 459.840 us; speedup vs baseline: 1.5608x; 1.0300x over previous
//
#include <hip/hip_runtime.h>

// NuclideGNN: 3-layer GCN on MI355X.
// R9:  block-per-node gather, LDS-staged indices, 2-deep row MLP.
// R10 (REVERTED): column-split gather -- 128B-line granularity, no win.
// R11 (REVERTED): wave-per-node -- halved MLP, BW 3.36->2.52 TB/s.
// R12 (REVERTED): scalar esrc loads put index latency on critical path.
// R13: residual chain bf16-only; -70MB/gather => gather not byte-bound.
// R14: uint4 row loads; VMEM insts x1/2 => -5%. 1.4M L2-miss lines/8 XCD
//     = 74us ~= measured 78 => gather L2-miss-service bound, at floor.
// R15: pA_bin LDS counting-sort -> contiguous window writes (-13us): the
//     random cross-XCD 4B scatter was line-ping-ponging.
// R16: CSR-build parallelism. Non-gather pool is ~248us and stable; p4 ran
//     only 196 blocks (<=1/CU). Buckets 512->256 nodes (NB=391, EMAX=10000):
//     p4 391 blocks x 512thr, half work/block; pA 512thr (halves serial
//     phase depth); wprep folded into inproj (one launch fewer).
//     Predict total 473.6 -> ~430-450; if <10us delta, CSR exonerated ->
//     pivot to fusion/roofline. Gather counters must stay byte-identical.

#define NN 100000
#define NE 3200000
#define FI 7
#define HD 128
#define DD 64
#define EPS 1e-5f
#define NB 391                        // buckets of 256 dst nodes (dst>>8)
#define EPB 8192                      // edges per pA block
#define NBLK ((NE + EPB - 1) / EPB)   // 391
#define EMAX 10000                    // fixed ebin window (max bucket ~8.7k)

typedef float float2v __attribute__((ext_vector_type(2)));
typedef short short8 __attribute__((ext_vector_type(8)));
typedef float f32x4 __attribute__((ext_vector_type(4)));
typedef unsigned uintv4 __attribute__((ext_vector_type(4)));

__device__ __forceinline__ unsigned char f2fp8(float f) {
    return (unsigned char)(__builtin_amdgcn_cvt_pk_fp8_f32(f, f, 0, false) & 0xFF);
}
__device__ __forceinline__ unsigned short f2bf(float f) {
    unsigned u = __float_as_uint(f);
    u += 0x7FFF + ((u >> 16) & 1);  // RNE
    return (unsigned short)(u >> 16);
}
__device__ __forceinline__ float bf2f(unsigned short s) {
    return __uint_as_float((unsigned)s << 16);
}

// ---------------- CSR build ----------------
// pA (R15/R16): per-block LDS counting-sort by 256-node bucket, then
// contiguous window writes. 512 threads.

__global__ __launch_bounds__(512) void pA_bin(const int* __restrict__ ei,
                                              int* __restrict__ bcnt,
                                              int* __restrict__ ebin) {
    __shared__ int rec[EPB];            // 32 KB reordered records
    __shared__ unsigned short bk[EPB];  // 16 KB bucket id per slot
    __shared__ int ls[512];             // scan buffer -> exclusive starts
    __shared__ int cur[NB];             // local cursors
    __shared__ int gb[NB];              // global window base per bucket
    __shared__ int hc[512];             // local bucket histogram
    const int t = threadIdx.x;
    const int base = blockIdx.x * EPB;
    const int cnt = min(EPB, NE - base);
    hc[t] = 0;
    __syncthreads();
    for (int i = t; i < cnt; i += 512)
        atomicAdd(&hc[ei[NE + base + i] >> 8], 1);
    __syncthreads();
    const int myc = hc[t];
    if (t < NB) gb[t] = (myc ? atomicAdd(&bcnt[t], myc) : 0) + t * EMAX;
    ls[t] = myc;
    __syncthreads();
    for (int off = 1; off < 512; off <<= 1) {
        int v = (t >= off) ? ls[t - off] : 0;
        __syncthreads();
        ls[t] += v;
        __syncthreads();
    }
    const int excl = ls[t] - myc;
    __syncthreads();
    ls[t] = excl;
    if (t < NB) cur[t] = excl;
    __syncthreads();
    // reorder records into LDS, sorted by bucket
    for (int i = t; i < cnt; i += 512) {
        int s = ei[base + i];
        int d = ei[NE + base + i];
        int b = d >> 8;
        int p = atomicAdd(&cur[b], 1);
        rec[p] = ((d & 255) << 23) | s;
        bk[p] = (unsigned short)b;
    }
    __syncthreads();
    // contiguous, single-XCD writes into each bucket's reserved run
    for (int i = t; i < cnt; i += 512) {
        int b = bk[i];
        ebin[gb[b] + (i - ls[b])] = rec[i];
    }
}

// p4: bucket-count scan (dense esrc offsets) + per-bucket hist/scan/scatter.
// R16: 391 blocks x 512 threads, 256 nodes per bucket.
__global__ __launch_bounds__(512) void p4_finalize(const int* __restrict__ bcnt,
                                                   const int* __restrict__ ebin,
                                                   int* __restrict__ esrc,
                                                   int* __restrict__ rowstart,
                                                   float* __restrict__ dinv) {
    __shared__ int sh[512];  // bucket-count scan
    __shared__ int lh[256];  // local degree
    __shared__ int sc[256];  // scan buffer
    __shared__ int lc[256];  // local cursor
    const int t = threadIdx.x;
    const int b = blockIdx.x;
    sh[t] = (t < NB) ? bcnt[t] : 0;
    __syncthreads();
    for (int off = 1; off < 512; off <<= 1) {
        int v = (t >= off) ? sh[t - off] : 0;
        __syncthreads();
        sh[t] += v;
        __syncthreads();
    }
    const int ecnt = bcnt[b];
    const int ebase = sh[b] - ecnt;   // dense esrc base for this bucket
    const int rbase = b * EMAX;       // padded ebin read base
    const int n0 = b << 8;
    if (t < 256) lh[t] = 0;
    __syncthreads();
    for (int i = t; i < ecnt; i += 512)
        atomicAdd(&lh[((unsigned)ebin[rbase + i]) >> 23], 1);
    __syncthreads();
    int c = 0;
    if (t < 256) { c = lh[t]; sc[t] = c; }
    __syncthreads();
    for (int off = 1; off < 256; off <<= 1) {
        int v = (t < 256 && t >= off) ? sc[t - off] : 0;
        __syncthreads();
        if (t < 256) sc[t] += v;
        __syncthreads();
    }
    if (t < 256) {
        const int excl = ebase + sc[t] - c;  // global rowstart for node n0+t
        lc[t] = excl;
        const int node = n0 + t;
        if (node < NN) {
            rowstart[node] = excl;
            dinv[node] = rsqrtf((float)c + 1.0f);  // deg includes self-loop
        }
    }
    if (b == NB - 1 && t == 0) rowstart[NN] = NE;
    __syncthreads();
    for (int i = t; i < ecnt; i += 512) {
        int v = ebin[rbase + i];
        int p = atomicAdd(&lc[((unsigned)v) >> 23], 1);
        esrc[p] = v & 0x7FFFFF;  // writes land in a 33KB L2-hot window
    }
}

// --------- input projection (bf16) + fused W pre-swizzle (R16) -------------
// Blocks [0, NN/2): inproj. Blocks [NN/2, NN/2+20): 80 wprep units (4/block).

__global__ __launch_bounds__(256) void inproj_wprep(const float* __restrict__ x,
                                                    const float* __restrict__ W_in,
                                                    const float* __restrict__ b_in,
                                                    unsigned short* __restrict__ hAbf,
                                                    const float* __restrict__ W0,
                                                    const float* __restrict__ W1,
                                                    const float* __restrict__ W2,
                                                    unsigned short* __restrict__ wf0,
                                                    unsigned short* __restrict__ wf1,
                                                    unsigned short* __restrict__ wf2) {
    const int blk = blockIdx.x;
    if (blk >= NN / 2) {
        const int u = (blk - NN / 2) * 4 + (threadIdx.x >> 6);
        if (u >= 80) return;
        const float* W;
        unsigned short* Wf;
        int DO, rel;
        if (u < 32) { W = W0; Wf = wf0; DO = 128; rel = u; }
        else if (u < 64) { W = W1; Wf = wf1; DO = 128; rel = u - 32; }
        else { W = W2; Wf = wf2; DO = 64; rel = u - 64; }
        const int lane = threadIdx.x & 63;
        const int nt = rel >> 2;
        const int ks = rel & 3;
        short8 o;
#pragma unroll
        for (int j = 0; j < 8; ++j)
            o[j] = (short)f2bf(W[(ks * 32 + (lane >> 4) * 8 + j) * DO + nt * 16 + (lane & 15)]);
        *(short8*)(Wf + ((size_t)rel * 64 + lane) * 8) = o;
        return;
    }
    int n = blk * 2 + (threadIdx.x >> 7);
    int j = threadIdx.x & 127;
    float acc = b_in[j];
#pragma unroll
    for (int f = 0; f < FI; ++f) acc += x[n * FI + f] * W_in[f * HD + j];
    acc = fmaxf(acc, 0.f);
    hAbf[n * HD + j] = f2bf(acc);
}

// -------- MFMA GEMM: B[N,DO](fp8) = (A[N,128](bf16) @ W) * dinv[row] --------

template <int DO>
__global__ __launch_bounds__(256) void gemm_mfma(const unsigned short* __restrict__ A,
                                                 const unsigned short* __restrict__ Wf,
                                                 const float* __restrict__ dinv,
                                                 unsigned char* __restrict__ B) {
    constexpr int CT = DO / 64;  // col-tiles per wave: 2 (DO=128) or 1 (DO=64)
    const int tid = threadIdx.x;
    const int wave = tid >> 6;
    const int lane = tid & 63;
    const int n0 = blockIdx.x * 32;
    short8 bfrag[CT][4];
#pragma unroll
    for (int ct = 0; ct < CT; ++ct)
#pragma unroll
        for (int ks = 0; ks < 4; ++ks)
            bfrag[ct][ks] = *(const short8*)(Wf + ((size_t)(((wave * CT + ct) * 4 + ks) * 64) + lane) * 8);
#pragma unroll
    for (int rt = 0; rt < 2; ++rt) {
        const int arow = n0 + rt * 16 + (lane & 15);
        short8 afrag[4];
#pragma unroll
        for (int ks = 0; ks < 4; ++ks)
            afrag[ks] = *(const short8*)(A + (size_t)arow * HD + ks * 32 + ((lane >> 4) & 3) * 8);
        f32x4 acc[CT];
#pragma unroll
        for (int ct = 0; ct < CT; ++ct) acc[ct] = (f32x4){0.f, 0.f, 0.f, 0.f};
#pragma unroll
        for (int ks = 0; ks < 4; ++ks)
#pragma unroll
            for (int ct = 0; ct < CT; ++ct)
                acc[ct] = __builtin_amdgcn_mfma_f32_16x16x32_bf16(afrag[ks], bfrag[ct][ks], acc[ct], 0, 0, 0);
#pragma unroll
        for (int r = 0; r < 4; ++r) {
            const int orow = n0 + rt * 16 + (lane >> 4) * 4 + r;
            const float dv = dinv[orow];
#pragma unroll
            for (int ct = 0; ct < CT; ++ct) {
                const int ocol = (wave * CT + ct) * 16 + (lane & 15);
                B[(size_t)orow * DO + ocol] = f2fp8(acc[ct][r] * dv);
            }
        }
    }
}

// ---------- fused gather (pure row-sum) + self-loop + bias + BN (+relu/res) --
// R14: block (128 thr) per dst node, s_idx LDS staging, 2-deep row MLP,
// uint4 (16B/lane) row loads: CG=DO/16 lanes per row, NG=128/CG edge groups.
// sred [16][132] (pad -> conflict-free), one output column per thread.

template <int DO, bool RELU_RES>
__global__ __launch_bounds__(128) void gather_kernel(const unsigned char* __restrict__ hXW,
                                                     float* __restrict__ resOut,
                                                     unsigned short* __restrict__ resBf,
                                                     const int* __restrict__ rowstart,
                                                     const int* __restrict__ esrc,
                                                     const float* __restrict__ dinv,
                                                     const float* __restrict__ bias,
                                                     const float* __restrict__ g,
                                                     const float* __restrict__ be,
                                                     const float* __restrict__ m,
                                                     const float* __restrict__ v) {
    constexpr int CG = DO / 16;   // lanes per row: 8 (DO=128) or 4 (DO=64)
    constexpr int NG = 128 / CG;  // edge groups: 16 or 32
    __shared__ int s_idx[128];
    __shared__ float sred[16][132];  // padded: write t-major, read k*CG+q
    const int n = blockIdx.x;
    const int t = threadIdx.x;
    const int rs = rowstart[n];
    const int re = rowstart[n + 1];
    const float dn = dinv[n];
    const int q = t & (CG - 1);
    const int grp = t / CG;
    float2v aL[4], aH[4], bL[4], bH[4];
#pragma unroll
    for (int w = 0; w < 4; ++w) {
        aL[w] = (float2v){0.f, 0.f}; aH[w] = (float2v){0.f, 0.f};
        bL[w] = (float2v){0.f, 0.f}; bH[w] = (float2v){0.f, 0.f};
    }
    for (int base = rs; base < re; base += 128) {
        const int c = min(128, re - base);
        __syncthreads();
        if (t < c) s_idx[t] = esrc[base + t];
        __syncthreads();
        for (int j = grp; j < c; j += 2 * NG) {
            {
                const uintv4 u = *(const uintv4*)(hXW + (size_t)s_idx[j] * DO + q * 16);
#pragma unroll
                for (int w = 0; w < 4; ++w) {
                    aL[w] += __builtin_amdgcn_cvt_pk_f32_fp8(u[w], false);
                    aH[w] += __builtin_amdgcn_cvt_pk_f32_fp8(u[w], true);
                }
            }
            if (j + NG < c) {
                const uintv4 u = *(const uintv4*)(hXW + (size_t)s_idx[j + NG] * DO + q * 16);
#pragma unroll
                for (int w = 0; w < 4; ++w) {
                    bL[w] += __builtin_amdgcn_cvt_pk_f32_fp8(u[w], false);
                    bH[w] += __builtin_amdgcn_cvt_pk_f32_fp8(u[w], true);
                }
            }
        }
    }
#pragma unroll
    for (int w = 0; w < 4; ++w) { aL[w] += bL[w]; aH[w] += bH[w]; }
#pragma unroll
    for (int w = 0; w < 4; ++w) {
        sred[4 * w + 0][t] = aL[w].x;
        sred[4 * w + 1][t] = aL[w].y;
        sred[4 * w + 2][t] = aH[w].x;
        sred[4 * w + 3][t] = aH[w].y;
    }
    __syncthreads();
    if (t < DO) {
        // col t: held by lanes with q2 = t>>4 at slot s = t&15
        const int s = t & 15;
        const int q2 = t >> 4;
        float sum = 0.f;
#pragma unroll
        for (int k = 0; k < NG; ++k) sum += sred[s][k * CG + q2];
        // self-loop: stored row n is already dinv[n]*XW[n]
        const unsigned su = *(const unsigned*)(hXW + (size_t)n * DO + (t & ~3));
        const float2v pLo = __builtin_amdgcn_cvt_pk_f32_fp8(su, false);
        const float2v pHi = __builtin_amdgcn_cvt_pk_f32_fp8(su, true);
        const float slf = (t & 2) ? ((t & 1) ? pHi.y : pHi.x)
                                  : ((t & 1) ? pLo.y : pLo.x);
        float val = (sum + slf) * dn + bias[t];
        val = (val - m[t]) * (g[t] * rsqrtf(v[t] + EPS)) + be[t];
        if (RELU_RES) {
            val = fmaxf(val, 0.f) + bf2f(resBf[(size_t)n * DO + t]);
            resBf[(size_t)n * DO + t] = f2bf(val);
        } else {
            resOut[(size_t)n * DO + t] = val;
        }
    }
}

// ---------------- launch ----------------

extern "C" void kernel_launch(void* const* d_in, const int* in_sizes, int n_in,
                              void* d_out, int out_size, void* d_ws, size_t ws_size,
                              hipStream_t stream) {
    const float* x    = (const float*)d_in[0];
    const int*   ei   = (const int*)d_in[1];
    const float* W_in = (const float*)d_in[2];
    const float* b_in = (const float*)d_in[3];
    const float* Wl[3] = {(const float*)d_in[4], (const float*)d_in[10], (const float*)d_in[16]};
    const float* bl[3] = {(const float*)d_in[5], (const float*)d_in[11], (const float*)d_in[17]};
    const float* gl[3] = {(const float*)d_in[6], (const float*)d_in[12], (const float*)d_in[18]};
    const float* bel[3] = {(const float*)d_in[7], (const float*)d_in[13], (const float*)d_in[19]};
    const float* ml[3] = {(const float*)d_in[8], (const float*)d_in[14], (const float*)d_in[20]};
    const float* vl[3] = {(const float*)d_in[9], (const float*)d_in[15], (const float*)d_in[21]};
    float* out = (float*)d_out;

    char* ws = (char*)d_ws;
    size_t off = 0;
    auto carve = [&](size_t bytes) {
        void* p = ws + off;
        off += (bytes + 255) & ~(size_t)255;
        return p;
    };
    int*   bcnt     = (int*)carve(NB * sizeof(int));
    int*   rowstart = (int*)carve((NN + 1) * sizeof(int));
    float* dinv     = (float*)carve(NN * sizeof(float));
    int*   esrc     = (int*)carve((size_t)NE * sizeof(int));
    unsigned short* hAbf = (unsigned short*)carve((size_t)NN * HD * sizeof(unsigned short));
    unsigned char* hB = (unsigned char*)carve((size_t)NN * HD);
    int*   ebin     = (int*)carve((size_t)NB * EMAX * sizeof(int));
    unsigned short* wf0 = (unsigned short*)carve((size_t)HD * HD * sizeof(unsigned short));
    unsigned short* wf1 = (unsigned short*)carve((size_t)HD * HD * sizeof(unsigned short));
    unsigned short* wf2 = (unsigned short*)carve((size_t)HD * DD * sizeof(unsigned short));
    (void)ws_size;

    hipMemsetAsync(bcnt, 0, NB * sizeof(int), stream);

    pA_bin<<<NBLK, 512, 0, stream>>>(ei, bcnt, ebin);
    p4_finalize<<<NB, 512, 0, stream>>>(bcnt, ebin, esrc, rowstart, dinv);

    inproj_wprep<<<NN / 2 + 20, 256, 0, stream>>>(x, W_in, b_in, hAbf,
                                                  Wl[0], Wl[1], Wl[2], wf0, wf1, wf2);

    // layer 0
    gemm_mfma<128><<<NN / 32, 256, 0, stream>>>(hAbf, wf0, dinv, hB);
    gather_kernel<128, true><<<NN, 128, 0, stream>>>(hB, (float*)nullptr, hAbf, rowstart, esrc, dinv,
                                                     bl[0], gl[0], bel[0], ml[0], vl[0]);
    // layer 1
    gemm_mfma<128><<<NN / 32, 256, 0, stream>>>(hAbf, wf1, dinv, hB);
    gather_kernel<128, true><<<NN, 128, 0, stream>>>(hB, (float*)nullptr, hAbf, rowstart, esrc, dinv,
                                                     bl[1], gl[1], bel[1], ml[1], vl[1]);
    // layer 2 (BN only, write d_out)
    gemm_mfma<64><<<NN / 32, 256, 0, stream>>>(hAbf, wf2, dinv, hB);
    gather_kernel<64, false><<<NN, 128, 0, stream>>>(hB, out, (unsigned short*)nullptr,
                                                     rowstart, esrc, dinv,
                                                     bl[2], gl[2], bel[2], ml[2], vl[2]);
}